// Round 6
// baseline (430.111 us; speedup 1.0000x reference)
//
#include <hip/hip_runtime.h>
#include <cstdint>
#include <cstddef>

#define NNODES 100000
#define NEDGES 1600000
#define FIN    128
#define HID    64
#define NCLS   40
#define CHUNK  1024
#define NBLK   ((NNODES + CHUNK - 1) / CHUNK)  // 98

// ---------------- Threefry-2x32 (JAX-compatible, partitionable) ----------------
__device__ __forceinline__ uint32_t rotl32(uint32_t x, uint32_t r) {
  return (x << r) | (x >> (32u - r));
}

__device__ __forceinline__ void threefry2x32(uint32_t k0, uint32_t k1,
                                             uint32_t c0, uint32_t c1,
                                             uint32_t& o0, uint32_t& o1) {
  const uint32_t ks2 = k0 ^ k1 ^ 0x1BD11BDAu;
  uint32_t x0 = c0 + k0;
  uint32_t x1 = c1 + k1;
#define TF_R(r) { x0 += x1; x1 = rotl32(x1, r); x1 ^= x0; }
  TF_R(13u) TF_R(15u) TF_R(26u) TF_R(6u)
  x0 += k1;  x1 += ks2 + 1u;
  TF_R(17u) TF_R(29u) TF_R(16u) TF_R(24u)
  x0 += ks2; x1 += k0 + 2u;
  TF_R(13u) TF_R(15u) TF_R(26u) TF_R(6u)
  x0 += k0;  x1 += k1 + 3u;
  TF_R(17u) TF_R(29u) TF_R(16u) TF_R(24u)
  x0 += k1;  x1 += ks2 + 4u;
  TF_R(13u) TF_R(15u) TF_R(26u) TF_R(6u)
  x0 += ks2; x1 += k0 + 5u;
#undef TF_R
  o0 = x0; o1 = x1;
}

// ---------------- CSR build ----------------
__global__ __launch_bounds__(256) void k_zero(int* __restrict__ cnt) {
  int i = blockIdx.x * 256 + threadIdx.x;
  if (i < NNODES) cnt[i] = 0;
}

__global__ __launch_bounds__(256) void k_count(const int* __restrict__ col,
                                               int* __restrict__ cnt) {
  int e = blockIdx.x * 256 + threadIdx.x;
  if (e < NEDGES) atomicAdd(&cnt[col[e]], 1);
}

__global__ __launch_bounds__(256) void k_dis(const int* __restrict__ cnt,
                                             float* __restrict__ dis) {
  int i = blockIdx.x * 256 + threadIdx.x;
  if (i < NNODES) dis[i] = rsqrtf((float)(cnt[i] + 1));
}

// phase 1: per-block local exclusive scan (into locs) + block total (partial[b])
__global__ __launch_bounds__(256) void k_scan1(const int* __restrict__ cnt,
                                               int* __restrict__ locs,
                                               int* __restrict__ partial) {
  const int b = blockIdx.x, t = threadIdx.x;
  const int base = b * CHUNK + t * 4;
  int4 v = make_int4(0, 0, 0, 0);
  if (base + 3 < NNODES) {
    v = *reinterpret_cast<const int4*>(cnt + base);
  } else {
    if (base + 0 < NNODES) v.x = cnt[base + 0];
    if (base + 1 < NNODES) v.y = cnt[base + 1];
    if (base + 2 < NNODES) v.z = cnt[base + 2];
    if (base + 3 < NNODES) v.w = cnt[base + 3];
  }
  const int s = v.x + v.y + v.z + v.w;
  const int lane = t & 63, wid = t >> 6;
  int sc = s;
#pragma unroll
  for (int off = 1; off < 64; off <<= 1) {
    int u = __shfl_up(sc, off, 64);
    if (lane >= off) sc += u;
  }
  __shared__ int wsum[4];
  if (lane == 63) wsum[wid] = sc;
  __syncthreads();
  int wadd = 0;
  for (int w = 0; w < wid; ++w) wadd += wsum[w];
  const int ex = sc - s + wadd;  // thread's exclusive prefix within block
  const int o0 = ex, o1 = ex + v.x, o2 = o1 + v.y, o3 = o2 + v.z;
  if (base + 3 < NNODES) {
    *reinterpret_cast<int4*>(locs + base) = make_int4(o0, o1, o2, o3);
  } else {
    if (base + 0 < NNODES) locs[base + 0] = o0;
    if (base + 1 < NNODES) locs[base + 1] = o1;
    if (base + 2 < NNODES) locs[base + 2] = o2;
    if (base + 3 < NNODES) locs[base + 3] = o3;
  }
  if (t == 255) partial[b] = ex + s;  // block total
}

// phase 2: one wave turns partial[] (NBLK totals) into exclusive block offsets
__global__ __launch_bounds__(64) void k_scan2(int* __restrict__ partial) {
  const int t = threadIdx.x;  // 0..63, covers 2 slots each
  const int i0 = 2 * t, i1 = 2 * t + 1;
  const int p0 = (i0 < NBLK) ? partial[i0] : 0;
  const int p1 = (i1 < NBLK) ? partial[i1] : 0;
  const int s = p0 + p1;
  int sc = s;
#pragma unroll
  for (int off = 1; off < 64; off <<= 1) {
    int u = __shfl_up(sc, off, 64);
    if (t >= off) sc += u;
  }
  const int ex = sc - s;
  if (i0 < NBLK) partial[i0] = ex;
  if (i1 < NBLK) partial[i1] = ex + p0;
}

// phase 3: offs = locs + partial[b]; cur = offs
__global__ __launch_bounds__(256) void k_scan3(const int* __restrict__ locs,
                                               const int* __restrict__ partial,
                                               int* __restrict__ offs,
                                               int* __restrict__ cur) {
  const int b = blockIdx.x, t = threadIdx.x;
  const int base = b * CHUNK + t * 4;
  const int add = partial[b];
  if (base + 3 < NNODES) {
    int4 v = *reinterpret_cast<const int4*>(locs + base);
    v.x += add; v.y += add; v.z += add; v.w += add;
    *reinterpret_cast<int4*>(offs + base) = v;
    *reinterpret_cast<int4*>(cur + base) = v;
  } else {
    for (int i = 0; i < 4; ++i) {
      if (base + i < NNODES) {
        int v = locs[base + i] + add;
        offs[base + i] = v;
        cur[base + i] = v;
      }
    }
  }
}

__global__ __launch_bounds__(256) void k_fill(const int* __restrict__ row,
                                              const int* __restrict__ col,
                                              int* __restrict__ cur,
                                              int* __restrict__ elist) {
  int e = blockIdx.x * 256 + threadIdx.x;
  if (e >= NEDGES) return;
  int pos = atomicAdd(&cur[col[e]], 1);
  // atomicExch instead of a plain store: scattered 4B stores write-through to
  // HBM at 64B granularity (measured 105.9 MB for a 6.4 MB array); the atomic
  // path executes memory-side in the LLC and dirty lines stay cached.
  atomicExch(&elist[pos], row[e]);
}

// ---------------- dense transforms, epilogue-scaled by dis[row] ----------------
__global__ __launch_bounds__(256) void k_mm1(const float* __restrict__ x,
                                             const float* __restrict__ W1,
                                             const float* __restrict__ dis,
                                             float* __restrict__ h1s) {
  __shared__ float wl[FIN * HID];
  const int t = threadIdx.x;
  for (int i = t; i < FIN * HID; i += 256) wl[i] = W1[i];
  __syncthreads();
  const int r = blockIdx.x * 256 + t;
  if (r >= NNODES) return;
  float acc[HID];
#pragma unroll
  for (int f = 0; f < HID; ++f) acc[f] = 0.f;
  const float* xr = x + (size_t)r * FIN;
  for (int k = 0; k < FIN; k += 4) {
    const float4 xv = *reinterpret_cast<const float4*>(xr + k);
    const float* w0 = &wl[k * HID];
#pragma unroll
    for (int f = 0; f < HID; ++f) {
      acc[f] += xv.x * w0[f] + xv.y * w0[HID + f] +
                xv.z * w0[2 * HID + f] + xv.w * w0[3 * HID + f];
    }
  }
  const float d = dis[r];
  float* hr = h1s + (size_t)r * HID;
#pragma unroll
  for (int f = 0; f < HID; f += 4) {
    *reinterpret_cast<float4*>(hr + f) =
        make_float4(acc[f] * d, acc[f + 1] * d, acc[f + 2] * d, acc[f + 3] * d);
  }
}

__global__ __launch_bounds__(256) void k_mm2(const float* __restrict__ h2,
                                             const float* __restrict__ W2,
                                             const float* __restrict__ dis,
                                             float* __restrict__ gs) {
  __shared__ float wl[HID * NCLS];
  const int t = threadIdx.x;
  for (int i = t; i < HID * NCLS; i += 256) wl[i] = W2[i];
  __syncthreads();
  const int r = blockIdx.x * 256 + t;
  if (r >= NNODES) return;
  float acc[NCLS];
#pragma unroll
  for (int f = 0; f < NCLS; ++f) acc[f] = 0.f;
  const float* xr = h2 + (size_t)r * HID;
  for (int k = 0; k < HID; k += 4) {
    const float4 xv = *reinterpret_cast<const float4*>(xr + k);
    const float* w0 = &wl[k * NCLS];
#pragma unroll
    for (int f = 0; f < NCLS; ++f) {
      acc[f] += xv.x * w0[f] + xv.y * w0[NCLS + f] +
                xv.z * w0[2 * NCLS + f] + xv.w * w0[3 * NCLS + f];
    }
  }
  const float d = dis[r];
  float* gr = gs + (size_t)r * NCLS;
#pragma unroll
  for (int f = 0; f < NCLS; f += 4) {
    *reinterpret_cast<float4*>(gr + f) =
        make_float4(acc[f] * d, acc[f + 1] * d, acc[f + 2] * d, acc[f + 3] * d);
  }
}

// ---------------- gather-aggregate layer 1 (+bias+relu+dropout) ----------------
__global__ __launch_bounds__(256) void k_agg1(const float* __restrict__ h1s,
                                              const int* __restrict__ elist,
                                              const int* __restrict__ offs,
                                              const int* __restrict__ cnt,
                                              const float* __restrict__ dis,
                                              const float* __restrict__ b1,
                                              float* __restrict__ h2) {
  const int gid = blockIdx.x * 256 + threadIdx.x;
  const int node = gid >> 6;
  const int lane = gid & 63;
  if (node >= NNODES) return;
  const int base = offs[node];
  const int n = cnt[node];
  float acc0 = h1s[(size_t)node * HID + lane];  // self term (h' = h*dis)
  float acc1 = 0.f, acc2 = 0.f, acc3 = 0.f;
  for (int k0 = 0; k0 < n; k0 += 64) {
    const int rem = n - k0;
    const int m = rem < 64 ? rem : 64;
    int src = 0;
    if (lane < m) src = elist[base + k0 + lane];
    int j = 0;
    for (; j + 4 <= m; j += 4) {
      const int s0 = __shfl(src, j, 64);
      const int s1 = __shfl(src, j + 1, 64);
      const int s2 = __shfl(src, j + 2, 64);
      const int s3 = __shfl(src, j + 3, 64);
      const float a0 = h1s[(size_t)s0 * HID + lane];
      const float a1 = h1s[(size_t)s1 * HID + lane];
      const float a2 = h1s[(size_t)s2 * HID + lane];
      const float a3 = h1s[(size_t)s3 * HID + lane];
      acc0 += a0; acc1 += a1; acc2 += a2; acc3 += a3;
    }
    for (; j < m; ++j) {
      const int s0 = __shfl(src, j, 64);
      acc0 += h1s[(size_t)s0 * HID + lane];
    }
  }
  const float acc = (acc0 + acc1) + (acc2 + acc3);
  float v = acc * dis[node] + b1[lane];
  v = fmaxf(v, 0.0f);
  const uint32_t idx = (uint32_t)node * HID + lane;
  uint32_t o0, o1;
  threefry2x32(0u, 42u, 0u, idx, o0, o1);
  const uint32_t bits = o0 ^ o1;
  const float u = __uint_as_float((bits >> 9) | 0x3f800000u) - 1.0f;
  const float keepf = (float)(1.0 - 0.4144);
  h2[idx] = (u < keepf) ? v / keepf : 0.0f;
}

// ---------------- gather-aggregate layer 2 (+bias+log_softmax) ----------------
__global__ __launch_bounds__(256) void k_agg2(const float* __restrict__ gs,
                                              const int* __restrict__ elist,
                                              const int* __restrict__ offs,
                                              const int* __restrict__ cnt,
                                              const float* __restrict__ dis,
                                              const float* __restrict__ b2,
                                              float* __restrict__ out) {
  const int gid = blockIdx.x * 256 + threadIdx.x;
  const int node = gid >> 6;
  const int lane = gid & 63;
  if (node >= NNODES) return;
  const int base = offs[node];
  const int n = cnt[node];
  float acc0 = (lane < NCLS) ? gs[(size_t)node * NCLS + lane] : 0.0f;
  float acc1 = 0.f, acc2 = 0.f, acc3 = 0.f;
  for (int k0 = 0; k0 < n; k0 += 64) {
    const int rem = n - k0;
    const int m = rem < 64 ? rem : 64;
    int src = 0;
    if (lane < m) src = elist[base + k0 + lane];
    int j = 0;
    for (; j + 4 <= m; j += 4) {
      const int s0 = __shfl(src, j, 64);
      const int s1 = __shfl(src, j + 1, 64);
      const int s2 = __shfl(src, j + 2, 64);
      const int s3 = __shfl(src, j + 3, 64);
      // loads stay within ws (gs aliases an N*64 region), lanes >= NCLS unused
      const float a0 = gs[(size_t)s0 * NCLS + lane];
      const float a1 = gs[(size_t)s1 * NCLS + lane];
      const float a2 = gs[(size_t)s2 * NCLS + lane];
      const float a3 = gs[(size_t)s3 * NCLS + lane];
      if (lane < NCLS) { acc0 += a0; acc1 += a1; acc2 += a2; acc3 += a3; }
    }
    for (; j < m; ++j) {
      const int s0 = __shfl(src, j, 64);
      if (lane < NCLS) acc0 += gs[(size_t)s0 * NCLS + lane];
    }
  }
  const float acc = (acc0 + acc1) + (acc2 + acc3);
  float v = (lane < NCLS) ? (acc * dis[node] + b2[lane]) : -INFINITY;
  float mx = v;
#pragma unroll
  for (int off = 32; off > 0; off >>= 1) mx = fmaxf(mx, __shfl_xor(mx, off, 64));
  float e = (lane < NCLS) ? expf(v - mx) : 0.0f;
  float s = e;
#pragma unroll
  for (int off = 32; off > 0; off >>= 1) s += __shfl_xor(s, off, 64);
  const float ls = logf(s);
  if (lane < NCLS) out[(size_t)node * NCLS + lane] = v - mx - ls;
}

// ---------------- launch ----------------
extern "C" void kernel_launch(void* const* d_in, const int* in_sizes, int n_in,
                              void* d_out, int out_size, void* d_ws, size_t ws_size,
                              hipStream_t stream) {
  const float* x  = (const float*)d_in[0];
  const int*   ei = (const int*)d_in[1];
  const float* W1 = (const float*)d_in[2];
  const float* b1 = (const float*)d_in[3];
  const float* W2 = (const float*)d_in[4];
  const float* b2 = (const float*)d_in[5];
  float* out = (float*)d_out;

  const int* row = ei;           // edge_index[0]  (source)
  const int* col = ei + NEDGES;  // edge_index[1]  (destination)

  float* ws  = (float*)d_ws;
  float* dis = ws;                          // N
  float* h1s = ws + 100352;                 // N*64  (reused as gs after agg1)
  float* h2  = h1s + (size_t)NNODES * HID;  // N*64
  int* cnt   = (int*)(h2 + (size_t)NNODES * HID);  // N
  int* offs  = cnt + NNODES;                       // N
  int* cur   = offs + NNODES;                      // N
  int* locs  = cur + NNODES;                       // N
  int* partial = locs + NNODES;                    // NBLK (+pad)
  int* elist = partial + 256;                      // E
  float* gs  = h1s;  // alias: h1s dead after k_agg1

  const dim3 B(256);
  const int GN  = (NNODES + 255) / 256;
  const int GE  = (NEDGES + 255) / 256;
  const int GNW = (NNODES * 64 + 255) / 256;  // wave per node

  // CSR build + normalization
  k_zero <<<dim3(GN), B, 0, stream>>>(cnt);
  k_count<<<dim3(GE), B, 0, stream>>>(col, cnt);
  k_dis  <<<dim3(GN), B, 0, stream>>>(cnt, dis);
  k_scan1<<<dim3(NBLK), B, 0, stream>>>(cnt, locs, partial);
  k_scan2<<<dim3(1), dim3(64), 0, stream>>>(partial);
  k_scan3<<<dim3(NBLK), B, 0, stream>>>(locs, partial, offs, cur);
  k_fill <<<dim3(GE), B, 0, stream>>>(row, col, cur, elist);

  // layer 1
  k_mm1 <<<dim3(GN), B, 0, stream>>>(x, W1, dis, h1s);
  k_agg1<<<dim3(GNW), B, 0, stream>>>(h1s, elist, offs, cnt, dis, b1, h2);

  // layer 2
  k_mm2 <<<dim3(GN), B, 0, stream>>>(h2, W2, dis, gs);
  k_agg2<<<dim3(GNW), B, 0, stream>>>(gs, elist, offs, cnt, dis, b2, out);
}

// Round 7
// 323.903 us; speedup vs baseline: 1.3279x; 1.3279x over previous
//
#include <hip/hip_runtime.h>
#include <cstdint>
#include <cstddef>

#define NNODES 100000
#define NEDGES 1600000
#define FIN    128
#define HID    64
#define NCLS   40
#define CHUNK  1024
#define NBLK   ((NNODES + CHUNK - 1) / CHUNK)  // 98
#define BSH    9                                // 512 nodes per bucket
#define NBUCK  ((NNODES + (1 << BSH) - 1) >> BSH)  // 196
#define EPB    8192                             // edges per k_bin block
#define NBINBLK ((NEDGES + EPB - 1) / EPB)      // 196
#define CSR_CAP 12288                           // max edges per bucket (mean 8192 + 45 sigma)

// ---------------- Threefry-2x32 (JAX-compatible, partitionable) ----------------
__device__ __forceinline__ uint32_t rotl32(uint32_t x, uint32_t r) {
  return (x << r) | (x >> (32u - r));
}

__device__ __forceinline__ void threefry2x32(uint32_t k0, uint32_t k1,
                                             uint32_t c0, uint32_t c1,
                                             uint32_t& o0, uint32_t& o1) {
  const uint32_t ks2 = k0 ^ k1 ^ 0x1BD11BDAu;
  uint32_t x0 = c0 + k0;
  uint32_t x1 = c1 + k1;
#define TF_R(r) { x0 += x1; x1 = rotl32(x1, r); x1 ^= x0; }
  TF_R(13u) TF_R(15u) TF_R(26u) TF_R(6u)
  x0 += k1;  x1 += ks2 + 1u;
  TF_R(17u) TF_R(29u) TF_R(16u) TF_R(24u)
  x0 += ks2; x1 += k0 + 2u;
  TF_R(13u) TF_R(15u) TF_R(26u) TF_R(6u)
  x0 += k0;  x1 += k1 + 3u;
  TF_R(17u) TF_R(29u) TF_R(16u) TF_R(24u)
  x0 += k1;  x1 += ks2 + 4u;
  TF_R(13u) TF_R(15u) TF_R(26u) TF_R(6u)
  x0 += ks2; x1 += k0 + 5u;
#undef TF_R
  o0 = x0; o1 = x1;
}

// ---------------- degree / normalization ----------------
__global__ __launch_bounds__(256) void k_zero(int* __restrict__ cnt) {
  int i = blockIdx.x * 256 + threadIdx.x;
  if (i < NNODES) cnt[i] = 0;
}

__global__ __launch_bounds__(256) void k_count(const int* __restrict__ col,
                                               int* __restrict__ cnt) {
  int e = blockIdx.x * 256 + threadIdx.x;
  if (e < NEDGES) atomicAdd(&cnt[col[e]], 1);
}

__global__ __launch_bounds__(256) void k_dis(const int* __restrict__ cnt,
                                             float* __restrict__ dis) {
  int i = blockIdx.x * 256 + threadIdx.x;
  if (i < NNODES) dis[i] = rsqrtf((float)(cnt[i] + 1));
}

// phase 1: per-block local exclusive scan (into locs) + block total (partial[b])
__global__ __launch_bounds__(256) void k_scan1(const int* __restrict__ cnt,
                                               int* __restrict__ locs,
                                               int* __restrict__ partial) {
  const int b = blockIdx.x, t = threadIdx.x;
  const int base = b * CHUNK + t * 4;
  int4 v = make_int4(0, 0, 0, 0);
  if (base + 3 < NNODES) {
    v = *reinterpret_cast<const int4*>(cnt + base);
  } else {
    if (base + 0 < NNODES) v.x = cnt[base + 0];
    if (base + 1 < NNODES) v.y = cnt[base + 1];
    if (base + 2 < NNODES) v.z = cnt[base + 2];
    if (base + 3 < NNODES) v.w = cnt[base + 3];
  }
  const int s = v.x + v.y + v.z + v.w;
  const int lane = t & 63, wid = t >> 6;
  int sc = s;
#pragma unroll
  for (int off = 1; off < 64; off <<= 1) {
    int u = __shfl_up(sc, off, 64);
    if (lane >= off) sc += u;
  }
  __shared__ int wsum[4];
  if (lane == 63) wsum[wid] = sc;
  __syncthreads();
  int wadd = 0;
  for (int w = 0; w < wid; ++w) wadd += wsum[w];
  const int ex = sc - s + wadd;  // thread's exclusive prefix within block
  const int o0 = ex, o1 = ex + v.x, o2 = o1 + v.y, o3 = o2 + v.z;
  if (base + 3 < NNODES) {
    *reinterpret_cast<int4*>(locs + base) = make_int4(o0, o1, o2, o3);
  } else {
    if (base + 0 < NNODES) locs[base + 0] = o0;
    if (base + 1 < NNODES) locs[base + 1] = o1;
    if (base + 2 < NNODES) locs[base + 2] = o2;
    if (base + 3 < NNODES) locs[base + 3] = o3;
  }
  if (t == 255) partial[b] = ex + s;  // block total
}

// phase 2: one wave turns partial[] (NBLK totals) into exclusive block offsets
__global__ __launch_bounds__(64) void k_scan2(int* __restrict__ partial) {
  const int t = threadIdx.x;  // 0..63, covers 2 slots each
  const int i0 = 2 * t, i1 = 2 * t + 1;
  const int p0 = (i0 < NBLK) ? partial[i0] : 0;
  const int p1 = (i1 < NBLK) ? partial[i1] : 0;
  const int s = p0 + p1;
  int sc = s;
#pragma unroll
  for (int off = 1; off < 64; off <<= 1) {
    int u = __shfl_up(sc, off, 64);
    if (t >= off) sc += u;
  }
  const int ex = sc - s;
  if (i0 < NBLK) partial[i0] = ex;
  if (i1 < NBLK) partial[i1] = ex + p0;
}

// phase 3: offs = locs + partial[b]
__global__ __launch_bounds__(256) void k_scan3(const int* __restrict__ locs,
                                               const int* __restrict__ partial,
                                               int* __restrict__ offs) {
  const int b = blockIdx.x, t = threadIdx.x;
  const int base = b * CHUNK + t * 4;
  const int add = partial[b];
  if (base + 3 < NNODES) {
    int4 v = *reinterpret_cast<const int4*>(locs + base);
    v.x += add; v.y += add; v.z += add; v.w += add;
    *reinterpret_cast<int4*>(offs + base) = v;
  } else {
    for (int i = 0; i < 4; ++i) {
      if (base + i < NNODES) offs[base + i] = locs[base + i] + add;
    }
  }
}

// per-bucket global cursors, init = bucket base in elist space
__global__ __launch_bounds__(256) void k_initcur(const int* __restrict__ offs,
                                                 int* __restrict__ gcur) {
  int b = threadIdx.x;
  if (b < NBUCK) gcur[b] = offs[b << BSH];
}

// ---------------- pass 1: bin (row,col) into bucket-major packed pairs --------
// LDS-staged so global writes are coalesced runs (scattered 4B stores write
// through at 64B granularity on non-coherent XCD L2s -- measured 100MB for a
// 6.4MB payload in rounds 5/6).
__global__ __launch_bounds__(256) void k_bin(const int* __restrict__ row,
                                             const int* __restrict__ col,
                                             int* __restrict__ gcur,
                                             uint32_t* __restrict__ pairs) {
  __shared__ int hcnt[256];
  __shared__ int sc[256];
  __shared__ int lofs[256];
  __shared__ int cur2[256];
  __shared__ int gofs[256];
  __shared__ uint32_t buf[EPB];
  __shared__ unsigned char bid[EPB];
  const int t = threadIdx.x;
  const int e0 = blockIdx.x * EPB;
  const int m = min(EPB, NEDGES - e0);
  hcnt[t] = 0;
  __syncthreads();
  for (int i = t; i < m; i += 256) {
    atomicAdd(&hcnt[col[e0 + i] >> BSH], 1);
  }
  __syncthreads();
  sc[t] = hcnt[t];
  __syncthreads();
  for (int d = 1; d < 256; d <<= 1) {
    int u = (t >= d) ? sc[t - d] : 0;
    __syncthreads();
    sc[t] += u;
    __syncthreads();
  }
  const int ex = sc[t] - hcnt[t];
  lofs[t] = ex;
  cur2[t] = ex;
  if (t < NBUCK) gofs[t] = atomicAdd(&gcur[t], hcnt[t]);
  __syncthreads();
  for (int i = t; i < m; i += 256) {
    const int c = col[e0 + i];
    const int r = row[e0 + i];
    const int b = c >> BSH;
    const int p = atomicAdd(&cur2[b], 1);
    buf[p] = ((uint32_t)r << BSH) | (uint32_t)(c & ((1 << BSH) - 1));
    bid[p] = (unsigned char)b;
  }
  __syncthreads();
  for (int i = t; i < m; i += 256) {
    const int b = bid[i];
    pairs[gofs[b] + (i - lofs[b])] = buf[i];
  }
}

// ---------------- pass 2: per-bucket LDS counting sort -> coalesced elist -----
__global__ __launch_bounds__(256) void k_csr(const uint32_t* __restrict__ pairs,
                                             const int* __restrict__ offs,
                                             int* __restrict__ elist) {
  __shared__ int ncur[1 << BSH];
  __shared__ int ebuf[CSR_CAP];
  const int b = blockIdx.x, t = threadIdx.x;
  const int nf = b << BSH;
  const int nodeCnt = min(1 << BSH, NNODES - nf);
  const int base = offs[nf];
  const int end = (b == NBUCK - 1) ? NEDGES : offs[nf + (1 << BSH)];
  const int ne = end - base;
  for (int n = t; n < nodeCnt; n += 256) ncur[n] = offs[nf + n] - base;
  __syncthreads();
  for (int i = t; i < ne; i += 256) {
    const uint32_t p = pairs[base + i];
    const int n = (int)(p & ((1 << BSH) - 1));
    const int slot = atomicAdd(&ncur[n], 1);
    ebuf[slot] = (int)(p >> BSH);
  }
  __syncthreads();
  for (int i = t; i < ne; i += 256) elist[base + i] = ebuf[i];
}

// ---------------- dense transforms, epilogue-scaled by dis[row] ----------------
__global__ __launch_bounds__(256) void k_mm1(const float* __restrict__ x,
                                             const float* __restrict__ W1,
                                             const float* __restrict__ dis,
                                             float* __restrict__ h1s) {
  __shared__ float wl[FIN * HID];
  const int t = threadIdx.x;
  for (int i = t; i < FIN * HID; i += 256) wl[i] = W1[i];
  __syncthreads();
  const int r = blockIdx.x * 256 + t;
  if (r >= NNODES) return;
  float acc[HID];
#pragma unroll
  for (int f = 0; f < HID; ++f) acc[f] = 0.f;
  const float* xr = x + (size_t)r * FIN;
  for (int k = 0; k < FIN; k += 4) {
    const float4 xv = *reinterpret_cast<const float4*>(xr + k);
    const float* w0 = &wl[k * HID];
#pragma unroll
    for (int f = 0; f < HID; ++f) {
      acc[f] += xv.x * w0[f] + xv.y * w0[HID + f] +
                xv.z * w0[2 * HID + f] + xv.w * w0[3 * HID + f];
    }
  }
  const float d = dis[r];
  float* hr = h1s + (size_t)r * HID;
#pragma unroll
  for (int f = 0; f < HID; f += 4) {
    *reinterpret_cast<float4*>(hr + f) =
        make_float4(acc[f] * d, acc[f + 1] * d, acc[f + 2] * d, acc[f + 3] * d);
  }
}

__global__ __launch_bounds__(256) void k_mm2(const float* __restrict__ h2,
                                             const float* __restrict__ W2,
                                             const float* __restrict__ dis,
                                             float* __restrict__ gs) {
  __shared__ float wl[HID * NCLS];
  const int t = threadIdx.x;
  for (int i = t; i < HID * NCLS; i += 256) wl[i] = W2[i];
  __syncthreads();
  const int r = blockIdx.x * 256 + t;
  if (r >= NNODES) return;
  float acc[NCLS];
#pragma unroll
  for (int f = 0; f < NCLS; ++f) acc[f] = 0.f;
  const float* xr = h2 + (size_t)r * HID;
  for (int k = 0; k < HID; k += 4) {
    const float4 xv = *reinterpret_cast<const float4*>(xr + k);
    const float* w0 = &wl[k * NCLS];
#pragma unroll
    for (int f = 0; f < NCLS; ++f) {
      acc[f] += xv.x * w0[f] + xv.y * w0[NCLS + f] +
                xv.z * w0[2 * NCLS + f] + xv.w * w0[3 * NCLS + f];
    }
  }
  const float d = dis[r];
  float* gr = gs + (size_t)r * NCLS;
#pragma unroll
  for (int f = 0; f < NCLS; f += 4) {
    *reinterpret_cast<float4*>(gr + f) =
        make_float4(acc[f] * d, acc[f + 1] * d, acc[f + 2] * d, acc[f + 3] * d);
  }
}

// ---------------- gather-aggregate layer 1 (+bias+relu+dropout) ----------------
__global__ __launch_bounds__(256) void k_agg1(const float* __restrict__ h1s,
                                              const int* __restrict__ elist,
                                              const int* __restrict__ offs,
                                              const int* __restrict__ cnt,
                                              const float* __restrict__ dis,
                                              const float* __restrict__ b1,
                                              float* __restrict__ h2) {
  const int gid = blockIdx.x * 256 + threadIdx.x;
  const int node = gid >> 6;
  const int lane = gid & 63;
  if (node >= NNODES) return;
  const int base = offs[node];
  const int n = cnt[node];
  float acc0 = h1s[(size_t)node * HID + lane];  // self term (h' = h*dis)
  float acc1 = 0.f, acc2 = 0.f, acc3 = 0.f;
  for (int k0 = 0; k0 < n; k0 += 64) {
    const int rem = n - k0;
    const int m = rem < 64 ? rem : 64;
    int src = 0;
    if (lane < m) src = elist[base + k0 + lane];
    int j = 0;
    for (; j + 4 <= m; j += 4) {
      const int s0 = __shfl(src, j, 64);
      const int s1 = __shfl(src, j + 1, 64);
      const int s2 = __shfl(src, j + 2, 64);
      const int s3 = __shfl(src, j + 3, 64);
      const float a0 = h1s[(size_t)s0 * HID + lane];
      const float a1 = h1s[(size_t)s1 * HID + lane];
      const float a2 = h1s[(size_t)s2 * HID + lane];
      const float a3 = h1s[(size_t)s3 * HID + lane];
      acc0 += a0; acc1 += a1; acc2 += a2; acc3 += a3;
    }
    for (; j < m; ++j) {
      const int s0 = __shfl(src, j, 64);
      acc0 += h1s[(size_t)s0 * HID + lane];
    }
  }
  const float acc = (acc0 + acc1) + (acc2 + acc3);
  float v = acc * dis[node] + b1[lane];
  v = fmaxf(v, 0.0f);
  const uint32_t idx = (uint32_t)node * HID + lane;
  uint32_t o0, o1;
  threefry2x32(0u, 42u, 0u, idx, o0, o1);
  const uint32_t bits = o0 ^ o1;
  const float u = __uint_as_float((bits >> 9) | 0x3f800000u) - 1.0f;
  const float keepf = (float)(1.0 - 0.4144);
  h2[idx] = (u < keepf) ? v / keepf : 0.0f;
}

// ---------------- gather-aggregate layer 2 (+bias+log_softmax) ----------------
__global__ __launch_bounds__(256) void k_agg2(const float* __restrict__ gs,
                                              const int* __restrict__ elist,
                                              const int* __restrict__ offs,
                                              const int* __restrict__ cnt,
                                              const float* __restrict__ dis,
                                              const float* __restrict__ b2,
                                              float* __restrict__ out) {
  const int gid = blockIdx.x * 256 + threadIdx.x;
  const int node = gid >> 6;
  const int lane = gid & 63;
  if (node >= NNODES) return;
  const int base = offs[node];
  const int n = cnt[node];
  float acc0 = (lane < NCLS) ? gs[(size_t)node * NCLS + lane] : 0.0f;
  float acc1 = 0.f, acc2 = 0.f, acc3 = 0.f;
  for (int k0 = 0; k0 < n; k0 += 64) {
    const int rem = n - k0;
    const int m = rem < 64 ? rem : 64;
    int src = 0;
    if (lane < m) src = elist[base + k0 + lane];
    int j = 0;
    for (; j + 4 <= m; j += 4) {
      const int s0 = __shfl(src, j, 64);
      const int s1 = __shfl(src, j + 1, 64);
      const int s2 = __shfl(src, j + 2, 64);
      const int s3 = __shfl(src, j + 3, 64);
      // loads stay within ws (gs aliases an N*64 region), lanes >= NCLS unused
      const float a0 = gs[(size_t)s0 * NCLS + lane];
      const float a1 = gs[(size_t)s1 * NCLS + lane];
      const float a2 = gs[(size_t)s2 * NCLS + lane];
      const float a3 = gs[(size_t)s3 * NCLS + lane];
      if (lane < NCLS) { acc0 += a0; acc1 += a1; acc2 += a2; acc3 += a3; }
    }
    for (; j < m; ++j) {
      const int s0 = __shfl(src, j, 64);
      if (lane < NCLS) acc0 += gs[(size_t)s0 * NCLS + lane];
    }
  }
  const float acc = (acc0 + acc1) + (acc2 + acc3);
  float v = (lane < NCLS) ? (acc * dis[node] + b2[lane]) : -INFINITY;
  float mx = v;
#pragma unroll
  for (int off = 32; off > 0; off >>= 1) mx = fmaxf(mx, __shfl_xor(mx, off, 64));
  float e = (lane < NCLS) ? expf(v - mx) : 0.0f;
  float s = e;
#pragma unroll
  for (int off = 32; off > 0; off >>= 1) s += __shfl_xor(s, off, 64);
  const float ls = logf(s);
  if (lane < NCLS) out[(size_t)node * NCLS + lane] = v - mx - ls;
}

// ---------------- launch ----------------
extern "C" void kernel_launch(void* const* d_in, const int* in_sizes, int n_in,
                              void* d_out, int out_size, void* d_ws, size_t ws_size,
                              hipStream_t stream) {
  const float* x  = (const float*)d_in[0];
  const int*   ei = (const int*)d_in[1];
  const float* W1 = (const float*)d_in[2];
  const float* b1 = (const float*)d_in[3];
  const float* W2 = (const float*)d_in[4];
  const float* b2 = (const float*)d_in[5];
  float* out = (float*)d_out;

  const int* row = ei;           // edge_index[0]  (source)
  const int* col = ei + NEDGES;  // edge_index[1]  (destination)

  float* ws  = (float*)d_ws;
  float* dis = ws;                          // N
  float* h1s = ws + 100352;                 // N*64  (reused as gs after agg1)
  float* h2  = h1s + (size_t)NNODES * HID;  // N*64
  int* cnt   = (int*)(h2 + (size_t)NNODES * HID);  // N
  int* offs  = cnt + NNODES;                       // N
  int* locs  = offs + NNODES;                      // N
  int* partial = locs + NNODES;                    // NBLK (+pad)
  int* gcur  = partial + 128;                      // NBUCK (+pad)
  int* elist = gcur + 256;                         // E
  uint32_t* pairs = (uint32_t*)h1s;  // alias: h1s not written until k_mm1
  float* gs  = h1s;                  // alias: h1s dead after k_agg1

  const dim3 B(256);
  const int GN  = (NNODES + 255) / 256;
  const int GE  = (NEDGES + 255) / 256;
  const int GNW = (NNODES * 64 + 255) / 256;  // wave per node

  // degree + offsets
  k_zero <<<dim3(GN), B, 0, stream>>>(cnt);
  k_count<<<dim3(GE), B, 0, stream>>>(col, cnt);
  k_dis  <<<dim3(GN), B, 0, stream>>>(cnt, dis);
  k_scan1<<<dim3(NBLK), B, 0, stream>>>(cnt, locs, partial);
  k_scan2<<<dim3(1), dim3(64), 0, stream>>>(partial);
  k_scan3<<<dim3(NBLK), B, 0, stream>>>(locs, partial, offs);

  // CSR build: bin + per-bucket counting sort (coalesced writes only)
  k_initcur<<<dim3(1), B, 0, stream>>>(offs, gcur);
  k_bin <<<dim3(NBINBLK), B, 0, stream>>>(row, col, gcur, pairs);
  k_csr <<<dim3(NBUCK), B, 0, stream>>>(pairs, offs, elist);

  // layer 1
  k_mm1 <<<dim3(GN), B, 0, stream>>>(x, W1, dis, h1s);
  k_agg1<<<dim3(GNW), B, 0, stream>>>(h1s, elist, offs, cnt, dis, b1, h2);

  // layer 2
  k_mm2 <<<dim3(GN), B, 0, stream>>>(h2, W2, dis, gs);
  k_agg2<<<dim3(GNW), B, 0, stream>>>(gs, elist, offs, cnt, dis, b2, out);
}

// Round 8
// 323.285 us; speedup vs baseline: 1.3304x; 1.0019x over previous
//
#include <hip/hip_runtime.h>
#include <cstdint>
#include <cstddef>

#define NNODES 100000
#define NEDGES 1600000
#define FIN    128
#define HID    64
#define NCLS   40
#define CHUNK  1024
#define NBLK   ((NNODES + CHUNK - 1) / CHUNK)  // 98
#define BSH    9                                // 512 nodes per bucket
#define NBUCK  ((NNODES + (1 << BSH) - 1) >> BSH)  // 196
#define EPB    8192                             // edges per k_bin block
#define NBINBLK ((NEDGES + EPB - 1) / EPB)      // 196
#define CSR_CAP 12288                           // max edges per bucket

// ---------------- bf16 helpers (storage-only precision cut) ----------------
__device__ __forceinline__ uint32_t bf16rne(float f) {
  uint32_t u = __float_as_uint(f);
  return (u + 0x7fffu + ((u >> 16) & 1u)) >> 16;
}
__device__ __forceinline__ float bfu(ushort us) {       // bf16 -> f32
  return __uint_as_float(((uint32_t)us) << 16);
}
__device__ __forceinline__ float bflo(uint32_t u) { return __uint_as_float(u << 16); }
__device__ __forceinline__ float bfhi(uint32_t u) { return __uint_as_float(u & 0xffff0000u); }
__device__ __forceinline__ uint32_t pk2(float a, float b) {
  return bf16rne(a) | (bf16rne(b) << 16);
}

// ---------------- Threefry-2x32 (JAX-compatible, partitionable) ----------------
__device__ __forceinline__ uint32_t rotl32(uint32_t x, uint32_t r) {
  return (x << r) | (x >> (32u - r));
}

__device__ __forceinline__ void threefry2x32(uint32_t k0, uint32_t k1,
                                             uint32_t c0, uint32_t c1,
                                             uint32_t& o0, uint32_t& o1) {
  const uint32_t ks2 = k0 ^ k1 ^ 0x1BD11BDAu;
  uint32_t x0 = c0 + k0;
  uint32_t x1 = c1 + k1;
#define TF_R(r) { x0 += x1; x1 = rotl32(x1, r); x1 ^= x0; }
  TF_R(13u) TF_R(15u) TF_R(26u) TF_R(6u)
  x0 += k1;  x1 += ks2 + 1u;
  TF_R(17u) TF_R(29u) TF_R(16u) TF_R(24u)
  x0 += ks2; x1 += k0 + 2u;
  TF_R(13u) TF_R(15u) TF_R(26u) TF_R(6u)
  x0 += k0;  x1 += k1 + 3u;
  TF_R(17u) TF_R(29u) TF_R(16u) TF_R(24u)
  x0 += k1;  x1 += ks2 + 4u;
  TF_R(13u) TF_R(15u) TF_R(26u) TF_R(6u)
  x0 += ks2; x1 += k0 + 5u;
#undef TF_R
  o0 = x0; o1 = x1;
}

// ---------------- degree / normalization ----------------
__global__ __launch_bounds__(256) void k_zero(int* __restrict__ cnt) {
  int i = blockIdx.x * 256 + threadIdx.x;
  if (i < NNODES) cnt[i] = 0;
}

__global__ __launch_bounds__(256) void k_count(const int* __restrict__ col,
                                               int* __restrict__ cnt) {
  int e = blockIdx.x * 256 + threadIdx.x;
  if (e < NEDGES) atomicAdd(&cnt[col[e]], 1);
}

__global__ __launch_bounds__(256) void k_dis(const int* __restrict__ cnt,
                                             float* __restrict__ dis) {
  int i = blockIdx.x * 256 + threadIdx.x;
  if (i < NNODES) dis[i] = rsqrtf((float)(cnt[i] + 1));
}

// phase 1: per-block local exclusive scan (into locs) + block total (partial[b])
__global__ __launch_bounds__(256) void k_scan1(const int* __restrict__ cnt,
                                               int* __restrict__ locs,
                                               int* __restrict__ partial) {
  const int b = blockIdx.x, t = threadIdx.x;
  const int base = b * CHUNK + t * 4;
  int4 v = make_int4(0, 0, 0, 0);
  if (base + 3 < NNODES) {
    v = *reinterpret_cast<const int4*>(cnt + base);
  } else {
    if (base + 0 < NNODES) v.x = cnt[base + 0];
    if (base + 1 < NNODES) v.y = cnt[base + 1];
    if (base + 2 < NNODES) v.z = cnt[base + 2];
    if (base + 3 < NNODES) v.w = cnt[base + 3];
  }
  const int s = v.x + v.y + v.z + v.w;
  const int lane = t & 63, wid = t >> 6;
  int sc = s;
#pragma unroll
  for (int off = 1; off < 64; off <<= 1) {
    int u = __shfl_up(sc, off, 64);
    if (lane >= off) sc += u;
  }
  __shared__ int wsum[4];
  if (lane == 63) wsum[wid] = sc;
  __syncthreads();
  int wadd = 0;
  for (int w = 0; w < wid; ++w) wadd += wsum[w];
  const int ex = sc - s + wadd;  // thread's exclusive prefix within block
  const int o0 = ex, o1 = ex + v.x, o2 = o1 + v.y, o3 = o2 + v.z;
  if (base + 3 < NNODES) {
    *reinterpret_cast<int4*>(locs + base) = make_int4(o0, o1, o2, o3);
  } else {
    if (base + 0 < NNODES) locs[base + 0] = o0;
    if (base + 1 < NNODES) locs[base + 1] = o1;
    if (base + 2 < NNODES) locs[base + 2] = o2;
    if (base + 3 < NNODES) locs[base + 3] = o3;
  }
  if (t == 255) partial[b] = ex + s;  // block total
}

// phase 2: one wave turns partial[] (NBLK totals) into exclusive block offsets
__global__ __launch_bounds__(64) void k_scan2(int* __restrict__ partial) {
  const int t = threadIdx.x;  // 0..63, covers 2 slots each
  const int i0 = 2 * t, i1 = 2 * t + 1;
  const int p0 = (i0 < NBLK) ? partial[i0] : 0;
  const int p1 = (i1 < NBLK) ? partial[i1] : 0;
  const int s = p0 + p1;
  int sc = s;
#pragma unroll
  for (int off = 1; off < 64; off <<= 1) {
    int u = __shfl_up(sc, off, 64);
    if (t >= off) sc += u;
  }
  const int ex = sc - s;
  if (i0 < NBLK) partial[i0] = ex;
  if (i1 < NBLK) partial[i1] = ex + p0;
}

// phase 3: offs = locs + partial[b]
__global__ __launch_bounds__(256) void k_scan3(const int* __restrict__ locs,
                                               const int* __restrict__ partial,
                                               int* __restrict__ offs) {
  const int b = blockIdx.x, t = threadIdx.x;
  const int base = b * CHUNK + t * 4;
  const int add = partial[b];
  if (base + 3 < NNODES) {
    int4 v = *reinterpret_cast<const int4*>(locs + base);
    v.x += add; v.y += add; v.z += add; v.w += add;
    *reinterpret_cast<int4*>(offs + base) = v;
  } else {
    for (int i = 0; i < 4; ++i) {
      if (base + i < NNODES) offs[base + i] = locs[base + i] + add;
    }
  }
}

// per-bucket global cursors, init = bucket base in elist space
__global__ __launch_bounds__(256) void k_initcur(const int* __restrict__ offs,
                                                 int* __restrict__ gcur) {
  int b = threadIdx.x;
  if (b < NBUCK) gcur[b] = offs[b << BSH];
}

// ---------------- pass 1: bin (row,col) into bucket-major packed pairs --------
__global__ __launch_bounds__(256) void k_bin(const int* __restrict__ row,
                                             const int* __restrict__ col,
                                             int* __restrict__ gcur,
                                             uint32_t* __restrict__ pairs) {
  __shared__ int hcnt[256];
  __shared__ int sc[256];
  __shared__ int lofs[256];
  __shared__ int cur2[256];
  __shared__ int gofs[256];
  __shared__ uint32_t buf[EPB];
  __shared__ unsigned char bid[EPB];
  const int t = threadIdx.x;
  const int e0 = blockIdx.x * EPB;
  const int m = min(EPB, NEDGES - e0);
  hcnt[t] = 0;
  __syncthreads();
  for (int i = t; i < m; i += 256) {
    atomicAdd(&hcnt[col[e0 + i] >> BSH], 1);
  }
  __syncthreads();
  sc[t] = hcnt[t];
  __syncthreads();
  for (int d = 1; d < 256; d <<= 1) {
    int u = (t >= d) ? sc[t - d] : 0;
    __syncthreads();
    sc[t] += u;
    __syncthreads();
  }
  const int ex = sc[t] - hcnt[t];
  lofs[t] = ex;
  cur2[t] = ex;
  if (t < NBUCK) gofs[t] = atomicAdd(&gcur[t], hcnt[t]);
  __syncthreads();
  for (int i = t; i < m; i += 256) {
    const int c = col[e0 + i];
    const int r = row[e0 + i];
    const int b = c >> BSH;
    const int p = atomicAdd(&cur2[b], 1);
    buf[p] = ((uint32_t)r << BSH) | (uint32_t)(c & ((1 << BSH) - 1));
    bid[p] = (unsigned char)b;
  }
  __syncthreads();
  for (int i = t; i < m; i += 256) {
    const int b = bid[i];
    pairs[gofs[b] + (i - lofs[b])] = buf[i];
  }
}

// ---------------- pass 2: per-bucket LDS counting sort -> coalesced elist -----
__global__ __launch_bounds__(256) void k_csr(const uint32_t* __restrict__ pairs,
                                             const int* __restrict__ offs,
                                             int* __restrict__ elist) {
  __shared__ int ncur[1 << BSH];
  __shared__ int ebuf[CSR_CAP];
  const int b = blockIdx.x, t = threadIdx.x;
  const int nf = b << BSH;
  const int nodeCnt = min(1 << BSH, NNODES - nf);
  const int base = offs[nf];
  const int end = (b == NBUCK - 1) ? NEDGES : offs[nf + (1 << BSH)];
  const int ne = end - base;
  for (int n = t; n < nodeCnt; n += 256) ncur[n] = offs[nf + n] - base;
  __syncthreads();
  for (int i = t; i < ne; i += 256) {
    const uint32_t p = pairs[base + i];
    const int n = (int)(p & ((1 << BSH) - 1));
    const int slot = atomicAdd(&ncur[n], 1);
    ebuf[slot] = (int)(p >> BSH);
  }
  __syncthreads();
  for (int i = t; i < ne; i += 256) elist[base + i] = ebuf[i];
}

// ---------------- mm1: h1s = bf16( (x @ W1) * dis[row] ), 2 rows/thread ------
__global__ __launch_bounds__(256) void k_mm1(const float* __restrict__ x,
                                             const float* __restrict__ W1,
                                             const float* __restrict__ dis,
                                             ushort* __restrict__ h1s) {
  __shared__ float wl[FIN * HID];
  const int t = threadIdx.x;
  for (int i = t; i < FIN * HID; i += 256) wl[i] = W1[i];
  __syncthreads();
  const int r0 = blockIdx.x * 512 + t;
  const int r1 = r0 + 256;
  if (r0 >= NNODES) return;
  const bool v1 = r1 < NNODES;
  float acc0[HID], acc1[HID];
#pragma unroll
  for (int f = 0; f < HID; ++f) { acc0[f] = 0.f; acc1[f] = 0.f; }
  const float* xr0 = x + (size_t)r0 * FIN;
  const float* xr1 = v1 ? x + (size_t)r1 * FIN : xr0;
  for (int k = 0; k < FIN; k += 4) {
    const float4 xa = *reinterpret_cast<const float4*>(xr0 + k);
    const float4 xb = *reinterpret_cast<const float4*>(xr1 + k);
    const float* w0 = &wl[k * HID];
#pragma unroll
    for (int f = 0; f < HID; ++f) {
      const float wa = w0[f], wb = w0[HID + f], wc = w0[2 * HID + f], wd = w0[3 * HID + f];
      acc0[f] += xa.x * wa + xa.y * wb + xa.z * wc + xa.w * wd;
      acc1[f] += xb.x * wa + xb.y * wb + xb.z * wc + xb.w * wd;
    }
  }
  {
    const float d = dis[r0];
    ushort* dst = h1s + (size_t)r0 * HID;
#pragma unroll
    for (int f = 0; f < HID; f += 8) {
      *reinterpret_cast<uint4*>(dst + f) = make_uint4(
          pk2(acc0[f] * d, acc0[f + 1] * d), pk2(acc0[f + 2] * d, acc0[f + 3] * d),
          pk2(acc0[f + 4] * d, acc0[f + 5] * d), pk2(acc0[f + 6] * d, acc0[f + 7] * d));
    }
  }
  if (v1) {
    const float d = dis[r1];
    ushort* dst = h1s + (size_t)r1 * HID;
#pragma unroll
    for (int f = 0; f < HID; f += 8) {
      *reinterpret_cast<uint4*>(dst + f) = make_uint4(
          pk2(acc1[f] * d, acc1[f + 1] * d), pk2(acc1[f + 2] * d, acc1[f + 3] * d),
          pk2(acc1[f + 4] * d, acc1[f + 5] * d), pk2(acc1[f + 6] * d, acc1[f + 7] * d));
    }
  }
}

// ---------------- mm2: gs = bf16( (h2 @ W2) * dis[row] ), 2 rows/thread ------
__global__ __launch_bounds__(256) void k_mm2(const ushort* __restrict__ h2,
                                             const float* __restrict__ W2,
                                             const float* __restrict__ dis,
                                             ushort* __restrict__ gs) {
  __shared__ float wl[HID * NCLS];
  const int t = threadIdx.x;
  for (int i = t; i < HID * NCLS; i += 256) wl[i] = W2[i];
  __syncthreads();
  const int r0 = blockIdx.x * 512 + t;
  const int r1 = r0 + 256;
  if (r0 >= NNODES) return;
  const bool v1 = r1 < NNODES;
  float acc0[NCLS], acc1[NCLS];
#pragma unroll
  for (int f = 0; f < NCLS; ++f) { acc0[f] = 0.f; acc1[f] = 0.f; }
  const ushort* h0 = h2 + (size_t)r0 * HID;
  const ushort* h1 = v1 ? h2 + (size_t)r1 * HID : h0;
  for (int k = 0; k < HID; k += 4) {
    const uint2 ua = *reinterpret_cast<const uint2*>(h0 + k);
    const uint2 ub = *reinterpret_cast<const uint2*>(h1 + k);
    const float a0 = bflo(ua.x), a1 = bfhi(ua.x), a2 = bflo(ua.y), a3 = bfhi(ua.y);
    const float b0 = bflo(ub.x), b1v = bfhi(ub.x), b2 = bflo(ub.y), b3 = bfhi(ub.y);
    const float* w0 = &wl[k * NCLS];
#pragma unroll
    for (int f = 0; f < NCLS; ++f) {
      const float wa = w0[f], wb = w0[NCLS + f], wc = w0[2 * NCLS + f], wd = w0[3 * NCLS + f];
      acc0[f] += a0 * wa + a1 * wb + a2 * wc + a3 * wd;
      acc1[f] += b0 * wa + b1v * wb + b2 * wc + b3 * wd;
    }
  }
  {
    const float d = dis[r0];
    ushort* dst = gs + (size_t)r0 * NCLS;
#pragma unroll
    for (int f = 0; f < NCLS; f += 4) {
      *reinterpret_cast<uint2*>(dst + f) =
          make_uint2(pk2(acc0[f] * d, acc0[f + 1] * d), pk2(acc0[f + 2] * d, acc0[f + 3] * d));
    }
  }
  if (v1) {
    const float d = dis[r1];
    ushort* dst = gs + (size_t)r1 * NCLS;
#pragma unroll
    for (int f = 0; f < NCLS; f += 4) {
      *reinterpret_cast<uint2*>(dst + f) =
          make_uint2(pk2(acc1[f] * d, acc1[f + 1] * d), pk2(acc1[f + 2] * d, acc1[f + 3] * d));
    }
  }
}

// ---------------- gather-aggregate layer 1 (+bias+relu+dropout) ----------------
__global__ __launch_bounds__(256) void k_agg1(const ushort* __restrict__ h1s,
                                              const int* __restrict__ elist,
                                              const int* __restrict__ offs,
                                              const int* __restrict__ cnt,
                                              const float* __restrict__ dis,
                                              const float* __restrict__ b1,
                                              ushort* __restrict__ h2) {
  const int gid = blockIdx.x * 256 + threadIdx.x;
  const int node = gid >> 6;
  const int lane = gid & 63;
  if (node >= NNODES) return;
  const int base = offs[node];
  const int n = cnt[node];
  float acc0 = bfu(h1s[(size_t)node * HID + lane]);  // self term (h' = h*dis)
  float acc1 = 0.f, acc2 = 0.f, acc3 = 0.f;
  for (int k0 = 0; k0 < n; k0 += 64) {
    const int rem = n - k0;
    const int m = rem < 64 ? rem : 64;
    int src = 0;
    if (lane < m) src = elist[base + k0 + lane];
    int j = 0;
    for (; j + 4 <= m; j += 4) {
      const int s0 = __shfl(src, j, 64);
      const int s1 = __shfl(src, j + 1, 64);
      const int s2 = __shfl(src, j + 2, 64);
      const int s3 = __shfl(src, j + 3, 64);
      const float a0 = bfu(h1s[(size_t)s0 * HID + lane]);
      const float a1 = bfu(h1s[(size_t)s1 * HID + lane]);
      const float a2 = bfu(h1s[(size_t)s2 * HID + lane]);
      const float a3 = bfu(h1s[(size_t)s3 * HID + lane]);
      acc0 += a0; acc1 += a1; acc2 += a2; acc3 += a3;
    }
    for (; j < m; ++j) {
      const int s0 = __shfl(src, j, 64);
      acc0 += bfu(h1s[(size_t)s0 * HID + lane]);
    }
  }
  const float acc = (acc0 + acc1) + (acc2 + acc3);
  float v = acc * dis[node] + b1[lane];
  v = fmaxf(v, 0.0f);
  const uint32_t idx = (uint32_t)node * HID + lane;
  uint32_t o0, o1;
  threefry2x32(0u, 42u, 0u, idx, o0, o1);
  const uint32_t bits = o0 ^ o1;
  const float u = __uint_as_float((bits >> 9) | 0x3f800000u) - 1.0f;
  const float keepf = (float)(1.0 - 0.4144);
  const float val = (u < keepf) ? v / keepf : 0.0f;
  h2[idx] = (ushort)bf16rne(val);
}

// ---------------- gather-aggregate layer 2 (+bias+log_softmax) ----------------
__global__ __launch_bounds__(256) void k_agg2(const ushort* __restrict__ gs,
                                              const int* __restrict__ elist,
                                              const int* __restrict__ offs,
                                              const int* __restrict__ cnt,
                                              const float* __restrict__ dis,
                                              const float* __restrict__ b2,
                                              float* __restrict__ out) {
  const int gid = blockIdx.x * 256 + threadIdx.x;
  const int node = gid >> 6;
  const int lane = gid & 63;
  if (node >= NNODES) return;
  const int base = offs[node];
  const int n = cnt[node];
  float acc0 = (lane < NCLS) ? bfu(gs[(size_t)node * NCLS + lane]) : 0.0f;
  float acc1 = 0.f, acc2 = 0.f, acc3 = 0.f;
  for (int k0 = 0; k0 < n; k0 += 64) {
    const int rem = n - k0;
    const int m = rem < 64 ? rem : 64;
    int src = 0;
    if (lane < m) src = elist[base + k0 + lane];
    int j = 0;
    for (; j + 4 <= m; j += 4) {
      const int s0 = __shfl(src, j, 64);
      const int s1 = __shfl(src, j + 1, 64);
      const int s2 = __shfl(src, j + 2, 64);
      const int s3 = __shfl(src, j + 3, 64);
      // reads stay within the ws allocation; lanes >= NCLS discarded
      const float a0 = bfu(gs[(size_t)s0 * NCLS + lane]);
      const float a1 = bfu(gs[(size_t)s1 * NCLS + lane]);
      const float a2 = bfu(gs[(size_t)s2 * NCLS + lane]);
      const float a3 = bfu(gs[(size_t)s3 * NCLS + lane]);
      if (lane < NCLS) { acc0 += a0; acc1 += a1; acc2 += a2; acc3 += a3; }
    }
    for (; j < m; ++j) {
      const int s0 = __shfl(src, j, 64);
      if (lane < NCLS) acc0 += bfu(gs[(size_t)s0 * NCLS + lane]);
    }
  }
  const float acc = (acc0 + acc1) + (acc2 + acc3);
  float v = (lane < NCLS) ? (acc * dis[node] + b2[lane]) : -INFINITY;
  float mx = v;
#pragma unroll
  for (int off = 32; off > 0; off >>= 1) mx = fmaxf(mx, __shfl_xor(mx, off, 64));
  float e = (lane < NCLS) ? expf(v - mx) : 0.0f;
  float s = e;
#pragma unroll
  for (int off = 32; off > 0; off >>= 1) s += __shfl_xor(s, off, 64);
  const float ls = logf(s);
  if (lane < NCLS) out[(size_t)node * NCLS + lane] = v - mx - ls;
}

// ---------------- launch ----------------
extern "C" void kernel_launch(void* const* d_in, const int* in_sizes, int n_in,
                              void* d_out, int out_size, void* d_ws, size_t ws_size,
                              hipStream_t stream) {
  const float* x  = (const float*)d_in[0];
  const int*   ei = (const int*)d_in[1];
  const float* W1 = (const float*)d_in[2];
  const float* b1 = (const float*)d_in[3];
  const float* W2 = (const float*)d_in[4];
  const float* b2 = (const float*)d_in[5];
  float* out = (float*)d_out;

  const int* row = ei;           // edge_index[0]  (source)
  const int* col = ei + NEDGES;  // edge_index[1]  (destination)

  float* ws  = (float*)d_ws;
  float* dis = ws;                                   // N f32
  ushort* h1s = (ushort*)(ws + 100352);              // N*64 bf16 (12.8 MB)
  ushort* h2  = h1s + (size_t)NNODES * HID;          // N*64 bf16
  int* cnt   = (int*)(h2 + (size_t)NNODES * HID);    // N
  int* offs  = cnt + NNODES;                         // N
  int* locs  = offs + NNODES;                        // N
  int* partial = locs + NNODES;                      // NBLK (+pad)
  int* gcur  = partial + 128;                        // NBUCK (+pad)
  int* elist = gcur + 256;                           // E
  uint32_t* pairs = (uint32_t*)h1s;  // alias: consumed by k_csr before k_mm1 writes h1s
  ushort* gs = h1s;                  // alias: h1s dead after k_agg1

  const dim3 B(256);
  const int GN  = (NNODES + 255) / 256;
  const int GE  = (NEDGES + 255) / 256;
  const int GNW = (NNODES * 64 + 255) / 256;   // wave per node
  const int GR2 = (NNODES + 511) / 512;        // 2 rows per thread

  // degree + offsets
  k_zero <<<dim3(GN), B, 0, stream>>>(cnt);
  k_count<<<dim3(GE), B, 0, stream>>>(col, cnt);
  k_dis  <<<dim3(GN), B, 0, stream>>>(cnt, dis);
  k_scan1<<<dim3(NBLK), B, 0, stream>>>(cnt, locs, partial);
  k_scan2<<<dim3(1), dim3(64), 0, stream>>>(partial);
  k_scan3<<<dim3(NBLK), B, 0, stream>>>(locs, partial, offs);

  // CSR build: bin + per-bucket counting sort (coalesced writes only)
  k_initcur<<<dim3(1), B, 0, stream>>>(offs, gcur);
  k_bin <<<dim3(NBINBLK), B, 0, stream>>>(row, col, gcur, pairs);
  k_csr <<<dim3(NBUCK), B, 0, stream>>>(pairs, offs, elist);

  // layer 1
  k_mm1 <<<dim3(GR2), B, 0, stream>>>(x, W1, dis, h1s);
  k_agg1<<<dim3(GNW), B, 0, stream>>>(h1s, elist, offs, cnt, dis, b1, h2);

  // layer 2
  k_mm2 <<<dim3(GR2), B, 0, stream>>>(h2, W2, dis, gs);
  k_agg2<<<dim3(GNW), B, 0, stream>>>(gs, elist, offs, cnt, dis, b2, out);
}

// Round 9
// 266.026 us; speedup vs baseline: 1.6168x; 1.2152x over previous
//
#include <hip/hip_runtime.h>
#include <cstdint>
#include <cstddef>

#define NNODES 100000
#define NEDGES 1600000
#define FIN    128
#define HID    64
#define NCLS   40
#define BSH    9                                   // 512 nodes per bucket
#define BNODES (1 << BSH)
#define NBUCK  ((NNODES + BNODES - 1) >> BSH)      // 196
#define EPB    8192                                // edges per k_bin block
#define NBINBLK ((NEDGES + EPB - 1) / EPB)         // 196
#define CSR_CAP 12288                              // slots per bucket (mean 8163 + 45 sigma)

// ---------------- bf16 helpers (storage-only precision cut) ----------------
__device__ __forceinline__ uint32_t bf16rne(float f) {
  uint32_t u = __float_as_uint(f);
  return (u + 0x7fffu + ((u >> 16) & 1u)) >> 16;
}
__device__ __forceinline__ float bfu(ushort us) { return __uint_as_float(((uint32_t)us) << 16); }
__device__ __forceinline__ float bflo(uint32_t u) { return __uint_as_float(u << 16); }
__device__ __forceinline__ float bfhi(uint32_t u) { return __uint_as_float(u & 0xffff0000u); }
__device__ __forceinline__ uint32_t pk2(float a, float b) {
  return bf16rne(a) | (bf16rne(b) << 16);
}

// ---------------- Threefry-2x32 (JAX-compatible, partitionable) ----------------
__device__ __forceinline__ uint32_t rotl32(uint32_t x, uint32_t r) {
  return (x << r) | (x >> (32u - r));
}

__device__ __forceinline__ void threefry2x32(uint32_t k0, uint32_t k1,
                                             uint32_t c0, uint32_t c1,
                                             uint32_t& o0, uint32_t& o1) {
  const uint32_t ks2 = k0 ^ k1 ^ 0x1BD11BDAu;
  uint32_t x0 = c0 + k0;
  uint32_t x1 = c1 + k1;
#define TF_R(r) { x0 += x1; x1 = rotl32(x1, r); x1 ^= x0; }
  TF_R(13u) TF_R(15u) TF_R(26u) TF_R(6u)
  x0 += k1;  x1 += ks2 + 1u;
  TF_R(17u) TF_R(29u) TF_R(16u) TF_R(24u)
  x0 += ks2; x1 += k0 + 2u;
  TF_R(13u) TF_R(15u) TF_R(26u) TF_R(6u)
  x0 += k0;  x1 += k1 + 3u;
  TF_R(17u) TF_R(29u) TF_R(16u) TF_R(24u)
  x0 += k1;  x1 += ks2 + 4u;
  TF_R(13u) TF_R(15u) TF_R(26u) TF_R(6u)
  x0 += ks2; x1 += k0 + 5u;
#undef TF_R
  o0 = x0; o1 = x1;
}

// ---------------- CSR build (no global degree counting) ----------------
// gcur[b] starts at b*CAP; k_bin reserves spans; counts derived afterwards.
__global__ __launch_bounds__(256) void k_initcur(int* __restrict__ gcur) {
  gcur[threadIdx.x] = threadIdx.x * CSR_CAP;
}

// pass 1: bin (row,col) into bucket-major packed pairs, LDS-staged so global
// writes are coalesced runs (scattered 4B stores write through at 64B
// granularity -- measured 100MB for a 6.4MB payload in rounds 5/6).
__global__ __launch_bounds__(256) void k_bin(const int* __restrict__ row,
                                             const int* __restrict__ col,
                                             int* __restrict__ gcur,
                                             uint32_t* __restrict__ pairs) {
  __shared__ int hcnt[256];
  __shared__ int sc[256];
  __shared__ int lofs[256];
  __shared__ int cur2[256];
  __shared__ int gofs[256];
  __shared__ uint32_t buf[EPB];
  __shared__ unsigned char bid[EPB];
  const int t = threadIdx.x;
  const int e0 = blockIdx.x * EPB;
  const int m = min(EPB, NEDGES - e0);
  hcnt[t] = 0;
  __syncthreads();
  for (int i = t; i < m; i += 256) {
    atomicAdd(&hcnt[col[e0 + i] >> BSH], 1);
  }
  __syncthreads();
  sc[t] = hcnt[t];
  __syncthreads();
  for (int d = 1; d < 256; d <<= 1) {
    int u = (t >= d) ? sc[t - d] : 0;
    __syncthreads();
    sc[t] += u;
    __syncthreads();
  }
  const int ex = sc[t] - hcnt[t];
  lofs[t] = ex;
  cur2[t] = ex;
  if (t < NBUCK) gofs[t] = atomicAdd(&gcur[t], hcnt[t]);
  __syncthreads();
  for (int i = t; i < m; i += 256) {
    const int c = col[e0 + i];
    const int r = row[e0 + i];
    const int b = c >> BSH;
    const int p = atomicAdd(&cur2[b], 1);
    buf[p] = ((uint32_t)r << BSH) | (uint32_t)(c & (BNODES - 1));
    bid[p] = (unsigned char)b;
  }
  __syncthreads();
  for (int i = t; i < m; i += 256) {
    const int b = bid[i];
    pairs[gofs[b] + (i - lofs[b])] = buf[i];
  }
}

// pass 2: one block scans the 196 bucket counts -> bbase (exclusive)
__global__ __launch_bounds__(256) void k_bscan(const int* __restrict__ gcur,
                                               int* __restrict__ bbase) {
  __shared__ int sc[256];
  __shared__ int cval[256];
  const int t = threadIdx.x;
  const int c = gcur[t] - t * CSR_CAP;  // bucket edge count (0 for t >= NBUCK)
  cval[t] = c;
  sc[t] = c;
  __syncthreads();
  for (int d = 1; d < 256; d <<= 1) {
    int u = (t >= d) ? sc[t - d] : 0;
    __syncthreads();
    sc[t] += u;
    __syncthreads();
  }
  bbase[t] = sc[t] - cval[t];
}

// pass 3: per-bucket LDS histogram + scan -> offs, dis; counting sort -> elist
__global__ __launch_bounds__(256) void k_csr(const uint32_t* __restrict__ pairs,
                                             const int* __restrict__ gcur,
                                             const int* __restrict__ bbase,
                                             int* __restrict__ offs,
                                             float* __restrict__ dis,
                                             int* __restrict__ elist) {
  __shared__ int hist[BNODES];
  __shared__ int ncur[BNODES];
  __shared__ int wsum[4];
  __shared__ int ebuf[CSR_CAP];
  const int b = blockIdx.x, t = threadIdx.x;
  const int nf = b << BSH;
  const int slot0 = b * CSR_CAP;
  const int ne = gcur[b] - slot0;
  const int base = bbase[b];
  hist[2 * t] = 0;
  hist[2 * t + 1] = 0;
  __syncthreads();
  for (int i = t; i < ne; i += 256) {
    atomicAdd(&hist[pairs[slot0 + i] & (BNODES - 1)], 1);
  }
  __syncthreads();
  // exclusive scan of hist[0..511]: thread t owns elements 2t, 2t+1
  const int a = hist[2 * t], c = hist[2 * t + 1];
  const int s = a + c;
  const int lane = t & 63, wid = t >> 6;
  int scv = s;
#pragma unroll
  for (int off = 1; off < 64; off <<= 1) {
    int u = __shfl_up(scv, off, 64);
    if (lane >= off) scv += u;
  }
  if (lane == 63) wsum[wid] = scv;
  __syncthreads();
  int wadd = 0;
  for (int w = 0; w < wid; ++w) wadd += wsum[w];
  const int ex = scv - s + wadd;  // exclusive prefix of s
  const int n0 = nf + 2 * t, n1 = nf + 2 * t + 1;
  if (n0 < NNODES) {
    offs[n0] = base + ex;
    dis[n0] = rsqrtf((float)(a + 1));
  }
  if (n1 < NNODES) {
    offs[n1] = base + ex + a;
    dis[n1] = rsqrtf((float)(c + 1));
  }
  if (b == NBUCK - 1 && t == 0) offs[NNODES] = base + ne;
  ncur[2 * t] = ex;
  ncur[2 * t + 1] = ex + a;
  __syncthreads();
  for (int i = t; i < ne; i += 256) {
    const uint32_t p = pairs[slot0 + i];
    const int n = (int)(p & (BNODES - 1));
    const int sl = atomicAdd(&ncur[n], 1);
    ebuf[sl] = (int)(p >> BSH);
  }
  __syncthreads();
  for (int i = t; i < ne; i += 256) elist[base + i] = ebuf[i];
}

// ---------------- mm1: h1s = bf16( (x @ W1) * dis[row] ), 1 row/thread ------
__global__ __launch_bounds__(256) void k_mm1(const float* __restrict__ x,
                                             const float* __restrict__ W1,
                                             const float* __restrict__ dis,
                                             ushort* __restrict__ h1s) {
  __shared__ float wl[FIN * HID];
  const int t = threadIdx.x;
  for (int i = t; i < FIN * HID; i += 256) wl[i] = W1[i];
  __syncthreads();
  const int r = blockIdx.x * 256 + t;
  if (r >= NNODES) return;
  float acc[HID];
#pragma unroll
  for (int f = 0; f < HID; ++f) acc[f] = 0.f;
  const float* xr = x + (size_t)r * FIN;
  for (int k = 0; k < FIN; k += 4) {
    const float4 xv = *reinterpret_cast<const float4*>(xr + k);
    const float* w0 = &wl[k * HID];
#pragma unroll
    for (int f = 0; f < HID; ++f) {
      acc[f] += xv.x * w0[f] + xv.y * w0[HID + f] +
                xv.z * w0[2 * HID + f] + xv.w * w0[3 * HID + f];
    }
  }
  const float d = dis[r];
  ushort* dst = h1s + (size_t)r * HID;
#pragma unroll
  for (int f = 0; f < HID; f += 8) {
    *reinterpret_cast<uint4*>(dst + f) = make_uint4(
        pk2(acc[f] * d, acc[f + 1] * d), pk2(acc[f + 2] * d, acc[f + 3] * d),
        pk2(acc[f + 4] * d, acc[f + 5] * d), pk2(acc[f + 6] * d, acc[f + 7] * d));
  }
}

// ---------------- mm2: gs = bf16( (h2 @ W2) * dis[row] ), 1 row/thread ------
__global__ __launch_bounds__(256) void k_mm2(const ushort* __restrict__ h2,
                                             const float* __restrict__ W2,
                                             const float* __restrict__ dis,
                                             ushort* __restrict__ gs) {
  __shared__ float wl[HID * NCLS];
  const int t = threadIdx.x;
  for (int i = t; i < HID * NCLS; i += 256) wl[i] = W2[i];
  __syncthreads();
  const int r = blockIdx.x * 256 + t;
  if (r >= NNODES) return;
  float acc[NCLS];
#pragma unroll
  for (int f = 0; f < NCLS; ++f) acc[f] = 0.f;
  const ushort* hr = h2 + (size_t)r * HID;
  for (int k = 0; k < HID; k += 4) {
    const uint2 ua = *reinterpret_cast<const uint2*>(hr + k);
    const float a0 = bflo(ua.x), a1 = bfhi(ua.x), a2 = bflo(ua.y), a3 = bfhi(ua.y);
    const float* w0 = &wl[k * NCLS];
#pragma unroll
    for (int f = 0; f < NCLS; ++f) {
      acc[f] += a0 * w0[f] + a1 * w0[NCLS + f] + a2 * w0[2 * NCLS + f] + a3 * w0[3 * NCLS + f];
    }
  }
  const float d = dis[r];
  ushort* dst = gs + (size_t)r * NCLS;
#pragma unroll
  for (int f = 0; f < NCLS; f += 4) {
    *reinterpret_cast<uint2*>(dst + f) =
        make_uint2(pk2(acc[f] * d, acc[f + 1] * d), pk2(acc[f + 2] * d, acc[f + 3] * d));
  }
}

// ---------------- gather-aggregate layer 1 (+bias+relu+dropout) ----------------
__global__ __launch_bounds__(256) void k_agg1(const ushort* __restrict__ h1s,
                                              const int* __restrict__ elist,
                                              const int* __restrict__ offs,
                                              const float* __restrict__ dis,
                                              const float* __restrict__ b1,
                                              ushort* __restrict__ h2) {
  const int gid = blockIdx.x * 256 + threadIdx.x;
  const int node = gid >> 6;
  const int lane = gid & 63;
  if (node >= NNODES) return;
  const int base = offs[node];
  const int n = offs[node + 1] - base;
  float acc0 = bfu(h1s[(size_t)node * HID + lane]);  // self term (h' = h*dis)
  float acc1 = 0.f, acc2 = 0.f, acc3 = 0.f;
  for (int k0 = 0; k0 < n; k0 += 64) {
    const int rem = n - k0;
    const int m = rem < 64 ? rem : 64;
    int src = 0;
    if (lane < m) src = elist[base + k0 + lane];
    int j = 0;
    for (; j + 4 <= m; j += 4) {
      const int s0 = __shfl(src, j, 64);
      const int s1 = __shfl(src, j + 1, 64);
      const int s2 = __shfl(src, j + 2, 64);
      const int s3 = __shfl(src, j + 3, 64);
      const float a0 = bfu(h1s[(size_t)s0 * HID + lane]);
      const float a1 = bfu(h1s[(size_t)s1 * HID + lane]);
      const float a2 = bfu(h1s[(size_t)s2 * HID + lane]);
      const float a3 = bfu(h1s[(size_t)s3 * HID + lane]);
      acc0 += a0; acc1 += a1; acc2 += a2; acc3 += a3;
    }
    for (; j < m; ++j) {
      const int s0 = __shfl(src, j, 64);
      acc0 += bfu(h1s[(size_t)s0 * HID + lane]);
    }
  }
  const float acc = (acc0 + acc1) + (acc2 + acc3);
  float v = acc * dis[node] + b1[lane];
  v = fmaxf(v, 0.0f);
  const uint32_t idx = (uint32_t)node * HID + lane;
  uint32_t o0, o1;
  threefry2x32(0u, 42u, 0u, idx, o0, o1);
  const uint32_t bits = o0 ^ o1;
  const float u = __uint_as_float((bits >> 9) | 0x3f800000u) - 1.0f;
  const float keepf = (float)(1.0 - 0.4144);
  const float val = (u < keepf) ? v / keepf : 0.0f;
  h2[idx] = (ushort)bf16rne(val);
}

// ---------------- gather-aggregate layer 2 (+bias+log_softmax) ----------------
__global__ __launch_bounds__(256) void k_agg2(const ushort* __restrict__ gs,
                                              const int* __restrict__ elist,
                                              const int* __restrict__ offs,
                                              const float* __restrict__ dis,
                                              const float* __restrict__ b2,
                                              float* __restrict__ out) {
  const int gid = blockIdx.x * 256 + threadIdx.x;
  const int node = gid >> 6;
  const int lane = gid & 63;
  if (node >= NNODES) return;
  const int base = offs[node];
  const int n = offs[node + 1] - base;
  float acc0 = (lane < NCLS) ? bfu(gs[(size_t)node * NCLS + lane]) : 0.0f;
  float acc1 = 0.f, acc2 = 0.f, acc3 = 0.f;
  for (int k0 = 0; k0 < n; k0 += 64) {
    const int rem = n - k0;
    const int m = rem < 64 ? rem : 64;
    int src = 0;
    if (lane < m) src = elist[base + k0 + lane];
    int j = 0;
    for (; j + 4 <= m; j += 4) {
      const int s0 = __shfl(src, j, 64);
      const int s1 = __shfl(src, j + 1, 64);
      const int s2 = __shfl(src, j + 2, 64);
      const int s3 = __shfl(src, j + 3, 64);
      // reads stay within the ws allocation; lanes >= NCLS discarded
      const float a0 = bfu(gs[(size_t)s0 * NCLS + lane]);
      const float a1 = bfu(gs[(size_t)s1 * NCLS + lane]);
      const float a2 = bfu(gs[(size_t)s2 * NCLS + lane]);
      const float a3 = bfu(gs[(size_t)s3 * NCLS + lane]);
      if (lane < NCLS) { acc0 += a0; acc1 += a1; acc2 += a2; acc3 += a3; }
    }
    for (; j < m; ++j) {
      const int s0 = __shfl(src, j, 64);
      if (lane < NCLS) acc0 += bfu(gs[(size_t)s0 * NCLS + lane]);
    }
  }
  const float acc = (acc0 + acc1) + (acc2 + acc3);
  float v = (lane < NCLS) ? (acc * dis[node] + b2[lane]) : -INFINITY;
  float mx = v;
#pragma unroll
  for (int off = 32; off > 0; off >>= 1) mx = fmaxf(mx, __shfl_xor(mx, off, 64));
  float e = (lane < NCLS) ? expf(v - mx) : 0.0f;
  float s = e;
#pragma unroll
  for (int off = 32; off > 0; off >>= 1) s += __shfl_xor(s, off, 64);
  const float ls = logf(s);
  if (lane < NCLS) out[(size_t)node * NCLS + lane] = v - mx - ls;
}

// ---------------- launch ----------------
extern "C" void kernel_launch(void* const* d_in, const int* in_sizes, int n_in,
                              void* d_out, int out_size, void* d_ws, size_t ws_size,
                              hipStream_t stream) {
  const float* x  = (const float*)d_in[0];
  const int*   ei = (const int*)d_in[1];
  const float* W1 = (const float*)d_in[2];
  const float* b1 = (const float*)d_in[3];
  const float* W2 = (const float*)d_in[4];
  const float* b2 = (const float*)d_in[5];
  float* out = (float*)d_out;

  const int* row = ei;           // edge_index[0]  (source)
  const int* col = ei + NEDGES;  // edge_index[1]  (destination)

  float* ws  = (float*)d_ws;
  float* dis = ws;                                   // N f32
  ushort* h1s = (ushort*)(ws + 100352);              // N*64 bf16 (12.8 MB)
  ushort* h2  = h1s + (size_t)NNODES * HID;          // N*64 bf16
  int* offs  = (int*)(h2 + (size_t)NNODES * HID);    // N+1
  int* gcur  = offs + NNODES + 64;                   // 256
  int* bbase = gcur + 256;                           // 256
  int* elist = bbase + 256;                          // E
  // pairs region: 196*12288*4B = 9.63 MB, aliases h1s (12.8 MB); consumed by
  // k_csr before k_mm1 writes h1s.
  uint32_t* pairs = (uint32_t*)h1s;
  ushort* gs = h1s;  // alias: h1s dead after k_agg1

  const dim3 B(256);
  const int GN  = (NNODES + 255) / 256;        // 391
  const int GNW = (NNODES * 64 + 255) / 256;   // wave per node

  // CSR build (bin -> bucket scan -> per-bucket sort); no global atoms on cnt
  k_initcur<<<dim3(1), B, 0, stream>>>(gcur);
  k_bin  <<<dim3(NBINBLK), B, 0, stream>>>(row, col, gcur, pairs);
  k_bscan<<<dim3(1), B, 0, stream>>>(gcur, bbase);
  k_csr  <<<dim3(NBUCK), B, 0, stream>>>(pairs, gcur, bbase, offs, dis, elist);

  // layer 1
  k_mm1 <<<dim3(GN), B, 0, stream>>>(x, W1, dis, h1s);
  k_agg1<<<dim3(GNW), B, 0, stream>>>(h1s, elist, offs, dis, b1, h2);

  // layer 2
  k_mm2 <<<dim3(GN), B, 0, stream>>>(h2, W2, dis, gs);
  k_agg2<<<dim3(GNW), B, 0, stream>>>(gs, elist, offs, dis, b2, out);
}

// Round 10
// 205.167 us; speedup vs baseline: 2.0964x; 1.2966x over previous
//
#include <hip/hip_runtime.h>
#include <cstdint>
#include <cstddef>

#define NNODES 100000
#define NEDGES 1600000
#define FIN    128
#define HID    64
#define NCLS   40
#define BSH    9                                   // 512 nodes per bucket
#define BNODES (1 << BSH)
#define NBUCK  ((NNODES + BNODES - 1) >> BSH)      // 196
#define EPB    8192                                // edges per k_bin block
#define NBINBLK ((NEDGES + EPB - 1) / EPB)         // 196
#define CSR_CAP 12288                              // slots per bucket

typedef __attribute__((ext_vector_type(8))) short bf16x8;
typedef __attribute__((ext_vector_type(16))) float f32x16;

// ---------------- bf16 helpers ----------------
__device__ __forceinline__ uint32_t bf16rne(float f) {
  uint32_t u = __float_as_uint(f);
  return (u + 0x7fffu + ((u >> 16) & 1u)) >> 16;
}
__device__ __forceinline__ float bfu(ushort us) { return __uint_as_float(((uint32_t)us) << 16); }

// ---------------- Threefry-2x32 (JAX-compatible, partitionable) ----------------
__device__ __forceinline__ uint32_t rotl32(uint32_t x, uint32_t r) {
  return (x << r) | (x >> (32u - r));
}

__device__ __forceinline__ void threefry2x32(uint32_t k0, uint32_t k1,
                                             uint32_t c0, uint32_t c1,
                                             uint32_t& o0, uint32_t& o1) {
  const uint32_t ks2 = k0 ^ k1 ^ 0x1BD11BDAu;
  uint32_t x0 = c0 + k0;
  uint32_t x1 = c1 + k1;
#define TF_R(r) { x0 += x1; x1 = rotl32(x1, r); x1 ^= x0; }
  TF_R(13u) TF_R(15u) TF_R(26u) TF_R(6u)
  x0 += k1;  x1 += ks2 + 1u;
  TF_R(17u) TF_R(29u) TF_R(16u) TF_R(24u)
  x0 += ks2; x1 += k0 + 2u;
  TF_R(13u) TF_R(15u) TF_R(26u) TF_R(6u)
  x0 += k0;  x1 += k1 + 3u;
  TF_R(17u) TF_R(29u) TF_R(16u) TF_R(24u)
  x0 += k1;  x1 += ks2 + 4u;
  TF_R(13u) TF_R(15u) TF_R(26u) TF_R(6u)
  x0 += ks2; x1 += k0 + 5u;
#undef TF_R
  o0 = x0; o1 = x1;
}

// ---------------- CSR build (no global degree counting) ----------------
__global__ __launch_bounds__(256) void k_initcur(int* __restrict__ gcur) {
  gcur[threadIdx.x] = threadIdx.x * CSR_CAP;
}

__global__ __launch_bounds__(256) void k_bin(const int* __restrict__ row,
                                             const int* __restrict__ col,
                                             int* __restrict__ gcur,
                                             uint32_t* __restrict__ pairs) {
  __shared__ int hcnt[256];
  __shared__ int sc[256];
  __shared__ int lofs[256];
  __shared__ int cur2[256];
  __shared__ int gofs[256];
  __shared__ uint32_t buf[EPB];
  __shared__ unsigned char bid[EPB];
  const int t = threadIdx.x;
  const int e0 = blockIdx.x * EPB;
  const int m = min(EPB, NEDGES - e0);
  hcnt[t] = 0;
  __syncthreads();
  for (int i = t; i < m; i += 256) {
    atomicAdd(&hcnt[col[e0 + i] >> BSH], 1);
  }
  __syncthreads();
  sc[t] = hcnt[t];
  __syncthreads();
  for (int d = 1; d < 256; d <<= 1) {
    int u = (t >= d) ? sc[t - d] : 0;
    __syncthreads();
    sc[t] += u;
    __syncthreads();
  }
  const int ex = sc[t] - hcnt[t];
  lofs[t] = ex;
  cur2[t] = ex;
  if (t < NBUCK) gofs[t] = atomicAdd(&gcur[t], hcnt[t]);
  __syncthreads();
  for (int i = t; i < m; i += 256) {
    const int c = col[e0 + i];
    const int r = row[e0 + i];
    const int b = c >> BSH;
    const int p = atomicAdd(&cur2[b], 1);
    buf[p] = ((uint32_t)r << BSH) | (uint32_t)(c & (BNODES - 1));
    bid[p] = (unsigned char)b;
  }
  __syncthreads();
  for (int i = t; i < m; i += 256) {
    const int b = bid[i];
    pairs[gofs[b] + (i - lofs[b])] = buf[i];
  }
}

__global__ __launch_bounds__(256) void k_bscan(const int* __restrict__ gcur,
                                               int* __restrict__ bbase) {
  __shared__ int sc[256];
  __shared__ int cval[256];
  const int t = threadIdx.x;
  const int c = gcur[t] - t * CSR_CAP;
  cval[t] = c;
  sc[t] = c;
  __syncthreads();
  for (int d = 1; d < 256; d <<= 1) {
    int u = (t >= d) ? sc[t - d] : 0;
    __syncthreads();
    sc[t] += u;
    __syncthreads();
  }
  bbase[t] = sc[t] - cval[t];
}

__global__ __launch_bounds__(256) void k_csr(const uint32_t* __restrict__ pairs,
                                             const int* __restrict__ gcur,
                                             const int* __restrict__ bbase,
                                             int* __restrict__ offs,
                                             float* __restrict__ dis,
                                             int* __restrict__ elist) {
  __shared__ int hist[BNODES];
  __shared__ int ncur[BNODES];
  __shared__ int wsum[4];
  __shared__ int ebuf[CSR_CAP];
  const int b = blockIdx.x, t = threadIdx.x;
  const int nf = b << BSH;
  const int slot0 = b * CSR_CAP;
  const int ne = gcur[b] - slot0;
  const int base = bbase[b];
  hist[2 * t] = 0;
  hist[2 * t + 1] = 0;
  __syncthreads();
  for (int i = t; i < ne; i += 256) {
    atomicAdd(&hist[pairs[slot0 + i] & (BNODES - 1)], 1);
  }
  __syncthreads();
  const int a = hist[2 * t], c = hist[2 * t + 1];
  const int s = a + c;
  const int lane = t & 63, wid = t >> 6;
  int scv = s;
#pragma unroll
  for (int off = 1; off < 64; off <<= 1) {
    int u = __shfl_up(scv, off, 64);
    if (lane >= off) scv += u;
  }
  if (lane == 63) wsum[wid] = scv;
  __syncthreads();
  int wadd = 0;
  for (int w = 0; w < wid; ++w) wadd += wsum[w];
  const int ex = scv - s + wadd;
  const int n0 = nf + 2 * t, n1 = nf + 2 * t + 1;
  if (n0 < NNODES) {
    offs[n0] = base + ex;
    dis[n0] = rsqrtf((float)(a + 1));
  }
  if (n1 < NNODES) {
    offs[n1] = base + ex + a;
    dis[n1] = rsqrtf((float)(c + 1));
  }
  if (b == NBUCK - 1 && t == 0) offs[NNODES] = base + ne;
  ncur[2 * t] = ex;
  ncur[2 * t + 1] = ex + a;
  __syncthreads();
  for (int i = t; i < ne; i += 256) {
    const uint32_t p = pairs[slot0 + i];
    const int n = (int)(p & (BNODES - 1));
    const int sl = atomicAdd(&ncur[n], 1);
    ebuf[sl] = (int)(p >> BSH);
  }
  __syncthreads();
  for (int i = t; i < ne; i += 256) elist[base + i] = ebuf[i];
}

// ---------------- mm1 (MFMA): h1s = bf16( (x @ W1) * dis[row] ) --------------
// 4 waves/block; each wave: 64 rows (2 row-tiles of 32) x 64 cols (2 col-tiles).
__global__ __launch_bounds__(256) void k_mm1(const float* __restrict__ x,
                                             const float* __restrict__ W1,
                                             const float* __restrict__ dis,
                                             ushort* __restrict__ h1s) {
  __shared__ ushort wl[FIN * HID];  // W1 as bf16, row-major [128][64]
  const int t = threadIdx.x;
  for (int i = t; i < FIN * HID; i += 256) wl[i] = (ushort)bf16rne(W1[i]);
  __syncthreads();

  const int lane = t & 63;
  const int wglob = blockIdx.x * 4 + (t >> 6);
  const int r0 = wglob * 64;
  if (r0 >= NNODES) return;
  const int c0 = lane & 31;
  const int hi8 = (lane >> 5) * 8;

  // B-fragments: wb{0,1}[ks], ks=0..7 (K=128)
  bf16x8 wb0[8], wb1[8];
#pragma unroll
  for (int ks = 0; ks < 8; ++ks) {
#pragma unroll
    for (int i = 0; i < 8; ++i) {
      const int k = ks * 16 + hi8 + i;
      wb0[ks][i] = (short)wl[k * HID + c0];
      wb1[ks][i] = (short)wl[k * HID + 32 + c0];
    }
  }

  const int ra = min(r0 + c0, NNODES - 1);
  const int rb = min(r0 + 32 + c0, NNODES - 1);
  f32x16 acc00 = {0}, acc01 = {0}, acc10 = {0}, acc11 = {0};
#pragma unroll
  for (int ks = 0; ks < 8; ++ks) {
    const int k0 = ks * 16 + hi8;
    const float4 fa0 = *reinterpret_cast<const float4*>(x + (size_t)ra * FIN + k0);
    const float4 fa1 = *reinterpret_cast<const float4*>(x + (size_t)ra * FIN + k0 + 4);
    const float4 fb0 = *reinterpret_cast<const float4*>(x + (size_t)rb * FIN + k0);
    const float4 fb1 = *reinterpret_cast<const float4*>(x + (size_t)rb * FIN + k0 + 4);
    bf16x8 a0, a1;
    a0[0] = (short)bf16rne(fa0.x); a0[1] = (short)bf16rne(fa0.y);
    a0[2] = (short)bf16rne(fa0.z); a0[3] = (short)bf16rne(fa0.w);
    a0[4] = (short)bf16rne(fa1.x); a0[5] = (short)bf16rne(fa1.y);
    a0[6] = (short)bf16rne(fa1.z); a0[7] = (short)bf16rne(fa1.w);
    a1[0] = (short)bf16rne(fb0.x); a1[1] = (short)bf16rne(fb0.y);
    a1[2] = (short)bf16rne(fb0.z); a1[3] = (short)bf16rne(fb0.w);
    a1[4] = (short)bf16rne(fb1.x); a1[5] = (short)bf16rne(fb1.y);
    a1[6] = (short)bf16rne(fb1.z); a1[7] = (short)bf16rne(fb1.w);
    acc00 = __builtin_amdgcn_mfma_f32_32x32x16_bf16(a0, wb0[ks], acc00, 0, 0, 0);
    acc01 = __builtin_amdgcn_mfma_f32_32x32x16_bf16(a0, wb1[ks], acc01, 0, 0, 0);
    acc10 = __builtin_amdgcn_mfma_f32_32x32x16_bf16(a1, wb0[ks], acc10, 0, 0, 0);
    acc11 = __builtin_amdgcn_mfma_f32_32x32x16_bf16(a1, wb1[ks], acc11, 0, 0, 0);
  }

  const int rrb = 4 * (lane >> 5);
#pragma unroll
  for (int reg = 0; reg < 16; ++reg) {
    const int rr = (reg & 3) + 8 * (reg >> 2) + rrb;
    const int r_a = r0 + rr;
    const int r_b = r0 + 32 + rr;
    if (r_a < NNODES) {
      const float d = dis[r_a];
      h1s[(size_t)r_a * HID + c0]      = (ushort)bf16rne(acc00[reg] * d);
      h1s[(size_t)r_a * HID + 32 + c0] = (ushort)bf16rne(acc01[reg] * d);
    }
    if (r_b < NNODES) {
      const float d = dis[r_b];
      h1s[(size_t)r_b * HID + c0]      = (ushort)bf16rne(acc10[reg] * d);
      h1s[(size_t)r_b * HID + 32 + c0] = (ushort)bf16rne(acc11[reg] * d);
    }
  }
}

// ---------------- mm2 (MFMA): gs = bf16( (h2 @ W2) * dis[row] ) --------------
// K=64, N=40 padded to 64 in LDS.
__global__ __launch_bounds__(256) void k_mm2(const ushort* __restrict__ h2,
                                             const float* __restrict__ W2,
                                             const float* __restrict__ dis,
                                             ushort* __restrict__ gs) {
  __shared__ ushort wl[HID * 64];  // [64][64], cols >= 40 zero
  const int t = threadIdx.x;
  for (int i = t; i < HID * 64; i += 256) {
    const int k = i >> 6, c = i & 63;
    wl[i] = (c < NCLS) ? (ushort)bf16rne(W2[k * NCLS + c]) : (ushort)0;
  }
  __syncthreads();

  const int lane = t & 63;
  const int wglob = blockIdx.x * 4 + (t >> 6);
  const int r0 = wglob * 64;
  if (r0 >= NNODES) return;
  const int c0 = lane & 31;
  const int hi8 = (lane >> 5) * 8;

  bf16x8 wb0[4], wb1[4];
#pragma unroll
  for (int ks = 0; ks < 4; ++ks) {
#pragma unroll
    for (int i = 0; i < 8; ++i) {
      const int k = ks * 16 + hi8 + i;
      wb0[ks][i] = (short)wl[k * 64 + c0];
      wb1[ks][i] = (short)wl[k * 64 + 32 + c0];
    }
  }

  const int ra = min(r0 + c0, NNODES - 1);
  const int rb = min(r0 + 32 + c0, NNODES - 1);
  f32x16 acc00 = {0}, acc01 = {0}, acc10 = {0}, acc11 = {0};
#pragma unroll
  for (int ks = 0; ks < 4; ++ks) {
    const int k0 = ks * 16 + hi8;
    const bf16x8 a0 = *reinterpret_cast<const bf16x8*>(h2 + (size_t)ra * HID + k0);
    const bf16x8 a1 = *reinterpret_cast<const bf16x8*>(h2 + (size_t)rb * HID + k0);
    acc00 = __builtin_amdgcn_mfma_f32_32x32x16_bf16(a0, wb0[ks], acc00, 0, 0, 0);
    acc01 = __builtin_amdgcn_mfma_f32_32x32x16_bf16(a0, wb1[ks], acc01, 0, 0, 0);
    acc10 = __builtin_amdgcn_mfma_f32_32x32x16_bf16(a1, wb0[ks], acc10, 0, 0, 0);
    acc11 = __builtin_amdgcn_mfma_f32_32x32x16_bf16(a1, wb1[ks], acc11, 0, 0, 0);
  }

  const int rrb = 4 * (lane >> 5);
  const bool c1ok = c0 < (NCLS - 32);  // cols 32..39 only
#pragma unroll
  for (int reg = 0; reg < 16; ++reg) {
    const int rr = (reg & 3) + 8 * (reg >> 2) + rrb;
    const int r_a = r0 + rr;
    const int r_b = r0 + 32 + rr;
    if (r_a < NNODES) {
      const float d = dis[r_a];
      gs[(size_t)r_a * NCLS + c0] = (ushort)bf16rne(acc00[reg] * d);
      if (c1ok) gs[(size_t)r_a * NCLS + 32 + c0] = (ushort)bf16rne(acc01[reg] * d);
    }
    if (r_b < NNODES) {
      const float d = dis[r_b];
      gs[(size_t)r_b * NCLS + c0] = (ushort)bf16rne(acc10[reg] * d);
      if (c1ok) gs[(size_t)r_b * NCLS + 32 + c0] = (ushort)bf16rne(acc11[reg] * d);
    }
  }
}

// ---------------- gather-aggregate layer 1 (+bias+relu+dropout) ----------------
__global__ __launch_bounds__(256) void k_agg1(const ushort* __restrict__ h1s,
                                              const int* __restrict__ elist,
                                              const int* __restrict__ offs,
                                              const float* __restrict__ dis,
                                              const float* __restrict__ b1,
                                              ushort* __restrict__ h2) {
  const int gid = blockIdx.x * 256 + threadIdx.x;
  const int node = gid >> 6;
  const int lane = gid & 63;
  if (node >= NNODES) return;
  const int base = offs[node];
  const int n = offs[node + 1] - base;
  float acc0 = bfu(h1s[(size_t)node * HID + lane]);
  float acc1 = 0.f, acc2 = 0.f, acc3 = 0.f;
  for (int k0 = 0; k0 < n; k0 += 64) {
    const int rem = n - k0;
    const int m = rem < 64 ? rem : 64;
    int src = 0;
    if (lane < m) src = elist[base + k0 + lane];
    int j = 0;
    for (; j + 4 <= m; j += 4) {
      const int s0 = __shfl(src, j, 64);
      const int s1 = __shfl(src, j + 1, 64);
      const int s2 = __shfl(src, j + 2, 64);
      const int s3 = __shfl(src, j + 3, 64);
      const float a0 = bfu(h1s[(size_t)s0 * HID + lane]);
      const float a1 = bfu(h1s[(size_t)s1 * HID + lane]);
      const float a2 = bfu(h1s[(size_t)s2 * HID + lane]);
      const float a3 = bfu(h1s[(size_t)s3 * HID + lane]);
      acc0 += a0; acc1 += a1; acc2 += a2; acc3 += a3;
    }
    for (; j < m; ++j) {
      const int s0 = __shfl(src, j, 64);
      acc0 += bfu(h1s[(size_t)s0 * HID + lane]);
    }
  }
  const float acc = (acc0 + acc1) + (acc2 + acc3);
  float v = acc * dis[node] + b1[lane];
  v = fmaxf(v, 0.0f);
  const uint32_t idx = (uint32_t)node * HID + lane;
  uint32_t o0, o1;
  threefry2x32(0u, 42u, 0u, idx, o0, o1);
  const uint32_t bits = o0 ^ o1;
  const float u = __uint_as_float((bits >> 9) | 0x3f800000u) - 1.0f;
  const float keepf = (float)(1.0 - 0.4144);
  const float val = (u < keepf) ? v / keepf : 0.0f;
  h2[idx] = (ushort)bf16rne(val);
}

// ---------------- gather-aggregate layer 2 (+bias+log_softmax) ----------------
__global__ __launch_bounds__(256) void k_agg2(const ushort* __restrict__ gs,
                                              const int* __restrict__ elist,
                                              const int* __restrict__ offs,
                                              const float* __restrict__ dis,
                                              const float* __restrict__ b2,
                                              float* __restrict__ out) {
  const int gid = blockIdx.x * 256 + threadIdx.x;
  const int node = gid >> 6;
  const int lane = gid & 63;
  if (node >= NNODES) return;
  const int base = offs[node];
  const int n = offs[node + 1] - base;
  float acc0 = (lane < NCLS) ? bfu(gs[(size_t)node * NCLS + lane]) : 0.0f;
  float acc1 = 0.f, acc2 = 0.f, acc3 = 0.f;
  for (int k0 = 0; k0 < n; k0 += 64) {
    const int rem = n - k0;
    const int m = rem < 64 ? rem : 64;
    int src = 0;
    if (lane < m) src = elist[base + k0 + lane];
    int j = 0;
    for (; j + 4 <= m; j += 4) {
      const int s0 = __shfl(src, j, 64);
      const int s1 = __shfl(src, j + 1, 64);
      const int s2 = __shfl(src, j + 2, 64);
      const int s3 = __shfl(src, j + 3, 64);
      const float a0 = bfu(gs[(size_t)s0 * NCLS + lane]);
      const float a1 = bfu(gs[(size_t)s1 * NCLS + lane]);
      const float a2 = bfu(gs[(size_t)s2 * NCLS + lane]);
      const float a3 = bfu(gs[(size_t)s3 * NCLS + lane]);
      if (lane < NCLS) { acc0 += a0; acc1 += a1; acc2 += a2; acc3 += a3; }
    }
    for (; j < m; ++j) {
      const int s0 = __shfl(src, j, 64);
      if (lane < NCLS) acc0 += bfu(gs[(size_t)s0 * NCLS + lane]);
    }
  }
  const float acc = (acc0 + acc1) + (acc2 + acc3);
  float v = (lane < NCLS) ? (acc * dis[node] + b2[lane]) : -INFINITY;
  float mx = v;
#pragma unroll
  for (int off = 32; off > 0; off >>= 1) mx = fmaxf(mx, __shfl_xor(mx, off, 64));
  float e = (lane < NCLS) ? expf(v - mx) : 0.0f;
  float s = e;
#pragma unroll
  for (int off = 32; off > 0; off >>= 1) s += __shfl_xor(s, off, 64);
  const float ls = logf(s);
  if (lane < NCLS) out[(size_t)node * NCLS + lane] = v - mx - ls;
}

// ---------------- launch ----------------
extern "C" void kernel_launch(void* const* d_in, const int* in_sizes, int n_in,
                              void* d_out, int out_size, void* d_ws, size_t ws_size,
                              hipStream_t stream) {
  const float* x  = (const float*)d_in[0];
  const int*   ei = (const int*)d_in[1];
  const float* W1 = (const float*)d_in[2];
  const float* b1 = (const float*)d_in[3];
  const float* W2 = (const float*)d_in[4];
  const float* b2 = (const float*)d_in[5];
  float* out = (float*)d_out;

  const int* row = ei;           // edge_index[0]  (source)
  const int* col = ei + NEDGES;  // edge_index[1]  (destination)

  float* ws  = (float*)d_ws;
  float* dis = ws;                                   // N f32
  ushort* h1s = (ushort*)(ws + 100352);              // N*64 bf16 (12.8 MB)
  ushort* h2  = h1s + (size_t)NNODES * HID;          // N*64 bf16
  int* offs  = (int*)(h2 + (size_t)NNODES * HID);    // N+1
  int* gcur  = offs + NNODES + 64;                   // 256
  int* bbase = gcur + 256;                           // 256
  int* elist = bbase + 256;                          // E
  uint32_t* pairs = (uint32_t*)h1s;  // alias: consumed by k_csr before k_mm1
  ushort* gs = h1s;                  // alias: h1s dead after k_agg1

  const dim3 B(256);
  const int GNW = (NNODES * 64 + 255) / 256;     // wave per node
  const int GMM = (NNODES + 255) / 256;          // 64 rows/wave * 4 waves = 256 rows/block

  // CSR build (bin -> bucket scan -> per-bucket sort)
  k_initcur<<<dim3(1), B, 0, stream>>>(gcur);
  k_bin  <<<dim3(NBINBLK), B, 0, stream>>>(row, col, gcur, pairs);
  k_bscan<<<dim3(1), B, 0, stream>>>(gcur, bbase);
  k_csr  <<<dim3(NBUCK), B, 0, stream>>>(pairs, gcur, bbase, offs, dis, elist);

  // layer 1
  k_mm1 <<<dim3(GMM), B, 0, stream>>>(x, W1, dis, h1s);
  k_agg1<<<dim3(GNW), B, 0, stream>>>(h1s, elist, offs, dis, b1, h2);

  // layer 2
  k_mm2 <<<dim3(GMM), B, 0, stream>>>(h2, W2, dis, gs);
  k_agg2<<<dim3(GNW), B, 0, stream>>>(gs, elist, offs, dis, b2, out);
}